// Round 1
// baseline (456.539 us; speedup 1.0000x reference)
//
#include <hip/hip_runtime.h>
#include <hip/hip_bf16.h>

// GraphSAGE forward: 2x SAGEConv(mean) + ReLU, then FC.
// N=40000 nodes, E=640000 edges, dims 128 -> 128 -> 64 -> 40.
// Strategy: build CSR once (hist + scan + place), gather-based mean agg
// (no float atomics), fused dual-GEMM fp32 vector kernels.

#define N_NODES 40000
#define N_EDGES 640000
#define D_IN    128
#define D_H1    128
#define D_H2    64
#define D_OUT   40

// ---------------- CSR build ----------------

__global__ void hist_k(const int* __restrict__ dst, int* __restrict__ deg) {
    int e = blockIdx.x * blockDim.x + threadIdx.x;
    if (e < N_EDGES) atomicAdd(&deg[dst[e]], 1);
}

__global__ void scan_k(const int* __restrict__ deg, int* __restrict__ offsets,
                       int* __restrict__ cursor, int n) {
    __shared__ int sm[1024];
    __shared__ int carry;
    int t = threadIdx.x;
    if (t == 0) carry = 0;
    __syncthreads();
    for (int base = 0; base < n; base += 1024) {
        int i = base + t;
        int v = (i < n) ? deg[i] : 0;
        sm[t] = v;
        __syncthreads();
        for (int s = 1; s < 1024; s <<= 1) {
            int u = (t >= s) ? sm[t - s] : 0;
            __syncthreads();
            sm[t] += u;
            __syncthreads();
        }
        int incl = sm[t];
        int c = carry;
        if (i < n) {
            int excl = c + incl - v;
            offsets[i] = excl;
            cursor[i] = excl;
        }
        __syncthreads();
        if (t == 1023) carry = c + incl;
        __syncthreads();
    }
    if (t == 0) offsets[n] = carry;
}

__global__ void place_k(const int* __restrict__ src, const int* __restrict__ dst,
                        int* __restrict__ cursor, int* __restrict__ src_sorted) {
    int e = blockIdx.x * blockDim.x + threadIdx.x;
    if (e < N_EDGES) {
        int p = atomicAdd(&cursor[dst[e]], 1);
        src_sorted[p] = src[e];
    }
}

// ---------------- mean aggregation (gather) ----------------
// one block (128 threads) per node; coalesced 512B row reads; loop uniform.

__global__ void agg_k(const float* __restrict__ feat, const int* __restrict__ offsets,
                      const int* __restrict__ src_sorted, float* __restrict__ mean_out) {
    int node = blockIdx.x;
    int d = threadIdx.x;
    int beg = offsets[node];
    int end = offsets[node + 1];
    float acc = 0.f;
    int i = beg;
    for (; i + 1 < end; i += 2) {
        int s0 = src_sorted[i];
        int s1 = src_sorted[i + 1];
        acc += feat[(size_t)s0 * 128 + d];
        acc += feat[(size_t)s1 * 128 + d];
    }
    if (i < end) acc += feat[(size_t)src_sorted[i] * 128 + d];
    int cnt = end - beg;
    float div = (float)(cnt > 1 ? cnt : 1);
    mean_out[(size_t)node * 128 + d] = acc / div;
}

// ---------------- fused dual GEMM + bias + relu ----------------
// out[M,NOUT] = relu(A1[M,128] @ W1[128,NOUT] + A2[M,128] @ W2[128,NOUT] + bias)
// 64 nodes per block, 256 threads. A tiles staged in LDS (padded stride 132).
// Weights (<=64KB each) stream through L1/L2 (resident across blocks).

template <int NOUT>
__global__ __launch_bounds__(256) void sage_gemm_k(
    const float* __restrict__ A1, const float* __restrict__ A2,
    const float* __restrict__ W1, const float* __restrict__ W2,
    const float* __restrict__ bias, float* __restrict__ out) {
    constexpr int CG  = NOUT / 4;   // col groups of 4
    constexpr int NL  = 256 / CG;   // node lanes
    constexpr int RPL = 64 / NL;    // rows per lane
    constexpr int LDW = 132;        // padded LDS row stride (floats)
    __shared__ float a_tile[64 * LDW];

    const int t = threadIdx.x;
    const int node0 = blockIdx.x * 64;
    const int c  = t % CG;
    const int nl = t / CG;

    float4 acc[RPL];
    {
        float4 b4 = *(const float4*)&bias[c * 4];
        #pragma unroll
        for (int r = 0; r < RPL; r++) acc[r] = b4;
    }

    for (int phase = 0; phase < 2; ++phase) {
        const float* __restrict__ A = phase ? A2 : A1;
        const float* __restrict__ W = phase ? W2 : W1;
        __syncthreads();  // protect previous phase's a_tile reads
        #pragma unroll
        for (int j = 0; j < 8; j++) {
            int fid = t + j * 256;      // 0..2047 : 64 rows x 32 float4
            int r = fid >> 5;
            int q = fid & 31;
            float4 v = *(const float4*)&A[(size_t)(node0 + r) * 128 + q * 4];
            *(float4*)&a_tile[r * LDW + q * 4] = v;
        }
        __syncthreads();
        for (int k = 0; k < 128; k += 4) {
            float4 a4[RPL];
            #pragma unroll
            for (int r = 0; r < RPL; r++)
                a4[r] = *(const float4*)&a_tile[(nl * RPL + r) * LDW + k];
            #pragma unroll
            for (int kk = 0; kk < 4; kk++) {
                float4 w4 = *(const float4*)&W[(size_t)(k + kk) * NOUT + c * 4];
                #pragma unroll
                for (int r = 0; r < RPL; r++) {
                    float a = (&a4[r].x)[kk];
                    acc[r].x += a * w4.x;
                    acc[r].y += a * w4.y;
                    acc[r].z += a * w4.z;
                    acc[r].w += a * w4.w;
                }
            }
        }
    }

    #pragma unroll
    for (int r = 0; r < RPL; r++) {
        float4 v = acc[r];
        v.x = fmaxf(v.x, 0.f);
        v.y = fmaxf(v.y, 0.f);
        v.z = fmaxf(v.z, 0.f);
        v.w = fmaxf(v.w, 0.f);
        *(float4*)&out[(size_t)(node0 + nl * RPL + r) * NOUT + c * 4] = v;
    }
}

// ---------------- final FC (no relu): logits = h2 @ Wfc + bfc ----------------

__global__ void fc_k(const float* __restrict__ h2, const float* __restrict__ W,
                     const float* __restrict__ b, float* __restrict__ out) {
    int idx = blockIdx.x * blockDim.x + threadIdx.x;
    if (idx >= N_NODES * D_OUT) return;
    int node = idx / D_OUT;
    int c = idx - node * D_OUT;
    float acc = b[c];
    const float* hrow = h2 + (size_t)node * D_H2;
    #pragma unroll 8
    for (int k = 0; k < D_H2; k++) acc += hrow[k] * W[k * D_OUT + c];
    out[idx] = acc;
}

// ---------------- launch ----------------

extern "C" void kernel_launch(void* const* d_in, const int* in_sizes, int n_in,
                              void* d_out, int out_size, void* d_ws, size_t ws_size,
                              hipStream_t stream) {
    const float* x       = (const float*)d_in[0];
    const int*   ei      = (const int*)d_in[1];
    const float* W1_nb   = (const float*)d_in[2];
    const float* b1      = (const float*)d_in[3];
    const float* W1_self = (const float*)d_in[4];
    const float* W2_nb   = (const float*)d_in[5];
    const float* b2      = (const float*)d_in[6];
    const float* W2_self = (const float*)d_in[7];
    const float* Wfc     = (const float*)d_in[8];
    const float* bfc     = (const float*)d_in[9];

    const int* src = ei;            // edge_index[0]
    const int* dst = ei + N_EDGES;  // edge_index[1]

    // workspace layout
    char* w = (char*)d_ws;
    int* deg        = (int*)w;                         // N
    int* offsets    = deg + N_NODES;                   // N+1
    int* cursor     = offsets + (N_NODES + 1);         // N
    int* src_sorted = cursor + N_NODES;                // E
    size_t int_bytes = ((size_t)(N_NODES * 3 + 1 + N_EDGES) * 4 + 15) & ~(size_t)15;
    float* mean = (float*)(w + int_bytes);             // N*128 (reused layer 2)
    float* h1   = mean + (size_t)N_NODES * 128;        // N*128

    float* emb    = (float*)d_out;                     // [N, 64]
    float* logits = emb + (size_t)N_NODES * D_H2;      // [N, 40]

    // 1. CSR build (shared by both layers)
    hipMemsetAsync(deg, 0, N_NODES * sizeof(int), stream);
    hist_k<<<(N_EDGES + 255) / 256, 256, 0, stream>>>(dst, deg);
    scan_k<<<1, 1024, 0, stream>>>(deg, offsets, cursor, N_NODES);
    place_k<<<(N_EDGES + 255) / 256, 256, 0, stream>>>(src, dst, cursor, src_sorted);

    // 2. layer 1
    agg_k<<<N_NODES, 128, 0, stream>>>(x, offsets, src_sorted, mean);
    sage_gemm_k<128><<<N_NODES / 64, 256, 0, stream>>>(mean, x, W1_nb, W1_self, b1, h1);

    // 3. layer 2 (reuse mean buffer)
    agg_k<<<N_NODES, 128, 0, stream>>>(h1, offsets, src_sorted, mean);
    sage_gemm_k<64><<<N_NODES / 64, 256, 0, stream>>>(mean, h1, W2_nb, W2_self, b2, emb);

    // 4. FC head
    fc_k<<<(N_NODES * D_OUT + 255) / 256, 256, 0, stream>>>(emb, Wfc, bfc, logits);
}

// Round 3
// 371.147 us; speedup vs baseline: 1.2301x; 1.2301x over previous
//
#include <hip/hip_runtime.h>
#include <hip/hip_bf16.h>

// GraphSAGE forward: 2x SAGEConv(mean) + ReLU, then FC.
// N=40000 nodes, E=640000 edges, dims 128 -> 128 -> 64 -> 40.
// R2 (resubmitted in R3; prior round hit GPU acquisition timeout):
// parallel 3-phase scan (was 1-block serial), float4 agg (8 nodes/blk),
// 32-row GEMM tiles for 2x occupancy (grid 625->1250, LDS 33.8->16.9KB).

#define N_NODES 40000
#define N_EDGES 640000
#define D_IN    128
#define D_H1    128
#define D_H2    64
#define D_OUT   40

#define SCAN_BLK 1024
#define N_SCAN_BLKS ((N_NODES + SCAN_BLK - 1) / SCAN_BLK)  // 40

// ---------------- CSR build ----------------

__global__ void hist_k(const int* __restrict__ dst, int* __restrict__ deg) {
    int e = blockIdx.x * blockDim.x + threadIdx.x;
    if (e < N_EDGES) atomicAdd(&deg[dst[e]], 1);
}

// phase 1: per-block (1024 elems) sums
__global__ __launch_bounds__(SCAN_BLK) void scan1_k(const int* __restrict__ deg,
                                                    int* __restrict__ blocksum) {
    __shared__ int wsum[SCAN_BLK / 64];
    int t = threadIdx.x;
    int i = blockIdx.x * SCAN_BLK + t;
    int v = (i < N_NODES) ? deg[i] : 0;
    #pragma unroll
    for (int s = 32; s > 0; s >>= 1) v += __shfl_down(v, s);
    if ((t & 63) == 0) wsum[t >> 6] = v;
    __syncthreads();
    if (t < SCAN_BLK / 64) {
        int x = wsum[t];
        #pragma unroll
        for (int s = SCAN_BLK / 128; s > 0; s >>= 1) x += __shfl_down(x, s);
        if (t == 0) blocksum[blockIdx.x] = x;
    }
}

// phase 2: tiny serial scan of 40 block sums (one thread; trivial)
__global__ void scan2_k(const int* __restrict__ blocksum, int* __restrict__ blockbase,
                        int* __restrict__ offsets) {
    if (threadIdx.x == 0 && blockIdx.x == 0) {
        int acc = 0;
        for (int b = 0; b < N_SCAN_BLKS; b++) { blockbase[b] = acc; acc += blocksum[b]; }
        offsets[N_NODES] = acc;
    }
}

// phase 3: block-local exclusive scan + base
__global__ __launch_bounds__(SCAN_BLK) void scan3_k(const int* __restrict__ deg,
                                                    const int* __restrict__ blockbase,
                                                    int* __restrict__ offsets,
                                                    int* __restrict__ cursor) {
    __shared__ int sm[SCAN_BLK];
    int t = threadIdx.x;
    int i = blockIdx.x * SCAN_BLK + t;
    int v = (i < N_NODES) ? deg[i] : 0;
    sm[t] = v;
    __syncthreads();
    for (int s = 1; s < SCAN_BLK; s <<= 1) {
        int u = (t >= s) ? sm[t - s] : 0;
        __syncthreads();
        sm[t] += u;
        __syncthreads();
    }
    if (i < N_NODES) {
        int excl = blockbase[blockIdx.x] + sm[t] - v;
        offsets[i] = excl;
        cursor[i] = excl;
    }
}

__global__ void place_k(const int* __restrict__ src, const int* __restrict__ dst,
                        int* __restrict__ cursor, int* __restrict__ src_sorted) {
    int e = blockIdx.x * blockDim.x + threadIdx.x;
    if (e < N_EDGES) {
        int p = atomicAdd(&cursor[dst[e]], 1);
        src_sorted[p] = src[e];
    }
}

// ---------------- mean aggregation (gather, float4) ----------------
// 8 nodes per 256-thread block; 32 lanes per node read the 512B row as float4.

__global__ __launch_bounds__(256) void agg_k(const float* __restrict__ feat,
                                             const int* __restrict__ offsets,
                                             const int* __restrict__ srcs,
                                             float* __restrict__ mean_out) {
    int t = threadIdx.x;
    int g = t >> 5;   // node group within block
    int q = t & 31;   // float4 index within row
    int node = blockIdx.x * 8 + g;
    int beg = offsets[node];
    int end = offsets[node + 1];
    float ax = 0.f, ay = 0.f, az = 0.f, aw = 0.f;
    int i = beg;
    for (; i + 4 <= end; i += 4) {
        int s0 = srcs[i], s1 = srcs[i + 1], s2 = srcs[i + 2], s3 = srcs[i + 3];
        float4 v0 = ((const float4*)(feat + (size_t)s0 * 128))[q];
        float4 v1 = ((const float4*)(feat + (size_t)s1 * 128))[q];
        float4 v2 = ((const float4*)(feat + (size_t)s2 * 128))[q];
        float4 v3 = ((const float4*)(feat + (size_t)s3 * 128))[q];
        ax += v0.x + v1.x + v2.x + v3.x;
        ay += v0.y + v1.y + v2.y + v3.y;
        az += v0.z + v1.z + v2.z + v3.z;
        aw += v0.w + v1.w + v2.w + v3.w;
    }
    for (; i < end; ++i) {
        float4 v = ((const float4*)(feat + (size_t)srcs[i] * 128))[q];
        ax += v.x; ay += v.y; az += v.z; aw += v.w;
    }
    int cnt = end - beg;
    float inv = 1.0f / (float)(cnt > 1 ? cnt : 1);
    float4 r; r.x = ax * inv; r.y = ay * inv; r.z = az * inv; r.w = aw * inv;
    ((float4*)(mean_out + (size_t)node * 128))[q] = r;
}

// ---------------- fused dual GEMM + bias + relu ----------------
// out[M,NOUT] = relu(A1@W1 + A2@W2 + bias). 32 nodes/block, 256 threads.

template <int NOUT>
__global__ __launch_bounds__(256) void sage_gemm_k(
    const float* __restrict__ A1, const float* __restrict__ A2,
    const float* __restrict__ W1, const float* __restrict__ W2,
    const float* __restrict__ bias, float* __restrict__ out) {
    constexpr int ROWS = 32;
    constexpr int CG  = NOUT / 4;    // col groups of 4
    constexpr int NL  = 256 / CG;    // node lanes
    constexpr int RPL = ROWS / NL;   // rows per lane (4 for 128, 2 for 64)
    constexpr int LDW = 132;         // padded LDS row stride (floats)
    __shared__ float a_tile[ROWS * LDW];

    const int t = threadIdx.x;
    const int node0 = blockIdx.x * ROWS;
    const int c  = t % CG;
    const int nl = t / CG;

    float4 acc[RPL];
    {
        float4 b4 = *(const float4*)&bias[c * 4];
        #pragma unroll
        for (int r = 0; r < RPL; r++) acc[r] = b4;
    }

    for (int phase = 0; phase < 2; ++phase) {
        const float* __restrict__ A = phase ? A2 : A1;
        const float* __restrict__ W = phase ? W2 : W1;
        __syncthreads();  // protect previous phase's a_tile reads
        #pragma unroll
        for (int j = 0; j < ROWS * 32 / 256; j++) {
            int fid = t + j * 256;      // ROWS rows x 32 float4
            int r = fid >> 5;
            int q = fid & 31;
            float4 v = *(const float4*)&A[(size_t)(node0 + r) * 128 + q * 4];
            *(float4*)&a_tile[r * LDW + q * 4] = v;
        }
        __syncthreads();
        for (int k = 0; k < 128; k += 4) {
            float4 a4[RPL];
            #pragma unroll
            for (int r = 0; r < RPL; r++)
                a4[r] = *(const float4*)&a_tile[(nl * RPL + r) * LDW + k];
            #pragma unroll
            for (int kk = 0; kk < 4; kk++) {
                float4 w4 = *(const float4*)&W[(size_t)(k + kk) * NOUT + c * 4];
                #pragma unroll
                for (int r = 0; r < RPL; r++) {
                    float a = (&a4[r].x)[kk];
                    acc[r].x += a * w4.x;
                    acc[r].y += a * w4.y;
                    acc[r].z += a * w4.z;
                    acc[r].w += a * w4.w;
                }
            }
        }
    }

    #pragma unroll
    for (int r = 0; r < RPL; r++) {
        float4 v = acc[r];
        v.x = fmaxf(v.x, 0.f);
        v.y = fmaxf(v.y, 0.f);
        v.z = fmaxf(v.z, 0.f);
        v.w = fmaxf(v.w, 0.f);
        *(float4*)&out[(size_t)(node0 + nl * RPL + r) * NOUT + c * 4] = v;
    }
}

// ---------------- final FC (no relu): logits = h2 @ Wfc + bfc ----------------

__global__ void fc_k(const float* __restrict__ h2, const float* __restrict__ W,
                     const float* __restrict__ b, float* __restrict__ out) {
    int idx = blockIdx.x * blockDim.x + threadIdx.x;
    if (idx >= N_NODES * D_OUT) return;
    int node = idx / D_OUT;
    int c = idx - node * D_OUT;
    float acc = b[c];
    const float4* h4 = (const float4*)(h2 + (size_t)node * D_H2);
    #pragma unroll
    for (int k4 = 0; k4 < D_H2 / 4; k4++) {
        float4 h = h4[k4];
        acc += h.x * W[(k4 * 4 + 0) * D_OUT + c];
        acc += h.y * W[(k4 * 4 + 1) * D_OUT + c];
        acc += h.z * W[(k4 * 4 + 2) * D_OUT + c];
        acc += h.w * W[(k4 * 4 + 3) * D_OUT + c];
    }
    out[idx] = acc;
}

// ---------------- launch ----------------

extern "C" void kernel_launch(void* const* d_in, const int* in_sizes, int n_in,
                              void* d_out, int out_size, void* d_ws, size_t ws_size,
                              hipStream_t stream) {
    const float* x       = (const float*)d_in[0];
    const int*   ei      = (const int*)d_in[1];
    const float* W1_nb   = (const float*)d_in[2];
    const float* b1      = (const float*)d_in[3];
    const float* W1_self = (const float*)d_in[4];
    const float* W2_nb   = (const float*)d_in[5];
    const float* b2      = (const float*)d_in[6];
    const float* W2_self = (const float*)d_in[7];
    const float* Wfc     = (const float*)d_in[8];
    const float* bfc     = (const float*)d_in[9];

    const int* src = ei;            // edge_index[0]
    const int* dst = ei + N_EDGES;  // edge_index[1]

    // workspace layout
    char* w = (char*)d_ws;
    int* deg        = (int*)w;                         // N
    int* offsets    = deg + N_NODES;                   // N+1
    int* cursor     = offsets + (N_NODES + 1);         // N
    int* blocksum   = cursor + N_NODES;                // 40
    int* blockbase  = blocksum + N_SCAN_BLKS;          // 40
    int* src_sorted = blockbase + N_SCAN_BLKS;         // E
    size_t int_elems = (size_t)N_NODES * 3 + 1 + 2 * N_SCAN_BLKS + N_EDGES;
    size_t int_bytes = (int_elems * 4 + 15) & ~(size_t)15;
    float* mean = (float*)(w + int_bytes);             // N*128 (reused layer 2)
    float* h1   = mean + (size_t)N_NODES * 128;        // N*128

    float* emb    = (float*)d_out;                     // [N, 64]
    float* logits = emb + (size_t)N_NODES * D_H2;      // [N, 40]

    // 1. CSR build (shared by both layers)
    hipMemsetAsync(deg, 0, N_NODES * sizeof(int), stream);
    hist_k<<<(N_EDGES + 255) / 256, 256, 0, stream>>>(dst, deg);
    scan1_k<<<N_SCAN_BLKS, SCAN_BLK, 0, stream>>>(deg, blocksum);
    scan2_k<<<1, 64, 0, stream>>>(blocksum, blockbase, offsets);
    scan3_k<<<N_SCAN_BLKS, SCAN_BLK, 0, stream>>>(deg, blockbase, offsets, cursor);
    place_k<<<(N_EDGES + 255) / 256, 256, 0, stream>>>(src, dst, cursor, src_sorted);

    // 2. layer 1
    agg_k<<<N_NODES / 8, 256, 0, stream>>>(x, offsets, src_sorted, mean);
    sage_gemm_k<128><<<N_NODES / 32, 256, 0, stream>>>(mean, x, W1_nb, W1_self, b1, h1);

    // 3. layer 2 (reuse mean buffer)
    agg_k<<<N_NODES / 8, 256, 0, stream>>>(h1, offsets, src_sorted, mean);
    sage_gemm_k<64><<<N_NODES / 32, 256, 0, stream>>>(mean, h1, W2_nb, W2_self, b2, emb);

    // 4. FC head
    fc_k<<<(N_NODES * D_OUT + 255) / 256, 256, 0, stream>>>(emb, Wfc, bfc, logits);
}

// Round 5
// 360.795 us; speedup vs baseline: 1.2654x; 1.0287x over previous
//
#include <hip/hip_runtime.h>
#include <hip/hip_bf16.h>

// GraphSAGE forward: 2x SAGEConv(mean) + ReLU, then FC.
// N=40000 nodes, E=640000 edges, dims 128 -> 128 -> 64 -> 40.
// R4 (resubmitted in R5; prior round hit GPU acquisition timeout):
// dual-GEMMs -> split-bf16 3-term MFMA (fp32-grade precision at bf16 rate).
// A staged in LDS as hi/lo bf16 with XOR swizzle; W pre-split/transposed once.

#define N_NODES 40000
#define N_EDGES 640000
#define D_IN    128
#define D_H1    128
#define D_H2    64
#define D_OUT   40

#define SCAN_BLK 1024
#define N_SCAN_BLKS ((N_NODES + SCAN_BLK - 1) / SCAN_BLK)  // 40

typedef __attribute__((ext_vector_type(8))) short short8v;
typedef __attribute__((ext_vector_type(4))) float float4v;

__device__ __forceinline__ unsigned short f2bf(float f) {
    unsigned u = __float_as_uint(f);
    unsigned r = u + 0x7FFFu + ((u >> 16) & 1u);   // RNE
    return (unsigned short)(r >> 16);
}
__device__ __forceinline__ float bf2f(unsigned short b) {
    return __uint_as_float(((unsigned)b) << 16);
}

// ---------------- CSR build ----------------

__global__ void hist_k(const int* __restrict__ dst, int* __restrict__ deg) {
    int e = blockIdx.x * blockDim.x + threadIdx.x;
    if (e < N_EDGES) atomicAdd(&deg[dst[e]], 1);
}

__global__ __launch_bounds__(SCAN_BLK) void scan1_k(const int* __restrict__ deg,
                                                    int* __restrict__ blocksum) {
    __shared__ int wsum[SCAN_BLK / 64];
    int t = threadIdx.x;
    int i = blockIdx.x * SCAN_BLK + t;
    int v = (i < N_NODES) ? deg[i] : 0;
    #pragma unroll
    for (int s = 32; s > 0; s >>= 1) v += __shfl_down(v, s);
    if ((t & 63) == 0) wsum[t >> 6] = v;
    __syncthreads();
    if (t < SCAN_BLK / 64) {
        int x = wsum[t];
        #pragma unroll
        for (int s = SCAN_BLK / 128; s > 0; s >>= 1) x += __shfl_down(x, s);
        if (t == 0) blocksum[blockIdx.x] = x;
    }
}

__global__ void scan2_k(const int* __restrict__ blocksum, int* __restrict__ blockbase,
                        int* __restrict__ offsets) {
    if (threadIdx.x == 0 && blockIdx.x == 0) {
        int acc = 0;
        for (int b = 0; b < N_SCAN_BLKS; b++) { blockbase[b] = acc; acc += blocksum[b]; }
        offsets[N_NODES] = acc;
    }
}

__global__ __launch_bounds__(SCAN_BLK) void scan3_k(const int* __restrict__ deg,
                                                    const int* __restrict__ blockbase,
                                                    int* __restrict__ offsets,
                                                    int* __restrict__ cursor) {
    __shared__ int sm[SCAN_BLK];
    int t = threadIdx.x;
    int i = blockIdx.x * SCAN_BLK + t;
    int v = (i < N_NODES) ? deg[i] : 0;
    sm[t] = v;
    __syncthreads();
    for (int s = 1; s < SCAN_BLK; s <<= 1) {
        int u = (t >= s) ? sm[t - s] : 0;
        __syncthreads();
        sm[t] += u;
        __syncthreads();
    }
    if (i < N_NODES) {
        int excl = blockbase[blockIdx.x] + sm[t] - v;
        offsets[i] = excl;
        cursor[i] = excl;
    }
}

__global__ void place_k(const int* __restrict__ src, const int* __restrict__ dst,
                        int* __restrict__ cursor, int* __restrict__ src_sorted) {
    int e = blockIdx.x * blockDim.x + threadIdx.x;
    if (e < N_EDGES) {
        int p = atomicAdd(&cursor[dst[e]], 1);
        src_sorted[p] = src[e];
    }
}

// ---------------- mean aggregation (gather, float4) ----------------

__global__ __launch_bounds__(256) void agg_k(const float* __restrict__ feat,
                                             const int* __restrict__ offsets,
                                             const int* __restrict__ srcs,
                                             float* __restrict__ mean_out) {
    int t = threadIdx.x;
    int g = t >> 5;
    int q = t & 31;
    int node = blockIdx.x * 8 + g;
    int beg = offsets[node];
    int end = offsets[node + 1];
    float ax = 0.f, ay = 0.f, az = 0.f, aw = 0.f;
    int i = beg;
    for (; i + 4 <= end; i += 4) {
        int s0 = srcs[i], s1 = srcs[i + 1], s2 = srcs[i + 2], s3 = srcs[i + 3];
        float4 v0 = ((const float4*)(feat + (size_t)s0 * 128))[q];
        float4 v1 = ((const float4*)(feat + (size_t)s1 * 128))[q];
        float4 v2 = ((const float4*)(feat + (size_t)s2 * 128))[q];
        float4 v3 = ((const float4*)(feat + (size_t)s3 * 128))[q];
        ax += v0.x + v1.x + v2.x + v3.x;
        ay += v0.y + v1.y + v2.y + v3.y;
        az += v0.z + v1.z + v2.z + v3.z;
        aw += v0.w + v1.w + v2.w + v3.w;
    }
    for (; i < end; ++i) {
        float4 v = ((const float4*)(feat + (size_t)srcs[i] * 128))[q];
        ax += v.x; ay += v.y; az += v.z; aw += v.w;
    }
    int cnt = end - beg;
    float inv = 1.0f / (float)(cnt > 1 ? cnt : 1);
    float4 r; r.x = ax * inv; r.y = ay * inv; r.z = az * inv; r.w = aw * inv;
    ((float4*)(mean_out + (size_t)node * 128))[q] = r;
}

// ---------------- W split+transpose: W[K][N] fp32 -> Wt_hi/lo[N][K] bf16 ----------------

__global__ void wsplit_k(const float* __restrict__ W, int K, int N,
                         short* __restrict__ Wt_hi, short* __restrict__ Wt_lo) {
    int tid = blockIdx.x * blockDim.x + threadIdx.x;
    if (tid >= K * N) return;
    int k = tid / N, n = tid - k * N;
    float w = W[tid];
    unsigned short h = f2bf(w);
    unsigned short lo = f2bf(w - bf2f(h));
    Wt_hi[n * K + k] = (short)h;
    Wt_lo[n * K + k] = (short)lo;
}

// ---------------- fused dual GEMM via split-bf16 MFMA ----------------
// out[64,NOUT] per block = relu(A1@W1 + A2@W2 + bias), K=128 each phase.
// 4 waves; wave w owns rows [w*16, w*16+16). mfma_f32_16x16x32_bf16:
//   A-frag: row = lane&15, k = (lane>>4)*8 + j (8 contiguous bf16)
//   B-frag: col = lane&15, same k mapping (W stored transposed [N][K])
//   C/D  : col = lane&15, row = (lane>>4)*4 + reg   [guide-verified m89/m91]

template <int NOUT>
__global__ __launch_bounds__(256) void sage_mfma_k(
    const float* __restrict__ A1, const float* __restrict__ A2,
    const short* __restrict__ W1h, const short* __restrict__ W1l,
    const short* __restrict__ W2h, const short* __restrict__ W2l,
    const float* __restrict__ bias, float* __restrict__ out) {
    constexpr int NT = NOUT / 16;          // 8 or 4 col tiles per wave
    __shared__ short a_hi_s[64 * 128];     // 16KB, row stride 256B, XOR-swizzled
    __shared__ short a_lo_s[64 * 128];     // 16KB

    const int t = threadIdx.x;
    const int w = t >> 6;
    const int l = t & 63;
    const int node0 = blockIdx.x * 64;
    const int ln16 = l & 15;
    const int kgrp = l >> 4;               // 0..3

    float4v acc[NT];
    #pragma unroll
    for (int ct = 0; ct < NT; ct++) {
        float bv = bias[ct * 16 + ln16];
        acc[ct] = (float4v){bv, bv, bv, bv};
    }

    const int arow = w * 16 + ln16;
    const int abase = arow * 256 + kgrp * 16;   // bytes; add kc*64, then XOR swizzle
    const int aswz = (l & 7) << 4;              // (arow&7)<<4 == (l&7)<<4

    for (int phase = 0; phase < 2; ++phase) {
        const float* __restrict__ A  = phase ? A2 : A1;
        const short* __restrict__ Wh = phase ? W2h : W1h;
        const short* __restrict__ Wl = phase ? W2l : W1l;

        __syncthreads();   // previous phase done reading LDS
        #pragma unroll
        for (int j = 0; j < 8; j++) {
            int fid = t + j * 256;             // 2048 float4 = 64 rows x 32
            int r = fid >> 5;
            int q = fid & 31;
            float4 v = *(const float4*)&A[(size_t)(node0 + r) * 128 + q * 4];
            unsigned short h0 = f2bf(v.x), h1 = f2bf(v.y), h2 = f2bf(v.z), h3 = f2bf(v.w);
            unsigned short e0 = f2bf(v.x - bf2f(h0)), e1 = f2bf(v.y - bf2f(h1));
            unsigned short e2 = f2bf(v.z - bf2f(h2)), e3 = f2bf(v.w - bf2f(h3));
            int byte = (r * 256 + q * 8) ^ ((r & 7) << 4);
            *(uint2*)((char*)a_hi_s + byte) =
                make_uint2((unsigned)h0 | ((unsigned)h1 << 16), (unsigned)h2 | ((unsigned)h3 << 16));
            *(uint2*)((char*)a_lo_s + byte) =
                make_uint2((unsigned)e0 | ((unsigned)e1 << 16), (unsigned)e2 | ((unsigned)e3 << 16));
        }
        __syncthreads();

        #pragma unroll
        for (int kc = 0; kc < 4; kc++) {
            int ab = (abase + kc * 64) ^ aswz;
            short8v ah = *(const short8v*)((const char*)a_hi_s + ab);
            short8v al = *(const short8v*)((const char*)a_lo_s + ab);
            #pragma unroll
            for (int ct = 0; ct < NT; ct++) {
                const size_t wo = (size_t)(ct * 16 + ln16) * 128 + kc * 32 + kgrp * 8;
                short8v bh = *(const short8v*)(Wh + wo);
                short8v bl = *(const short8v*)(Wl + wo);
                acc[ct] = __builtin_amdgcn_mfma_f32_16x16x32_bf16(ah, bh, acc[ct], 0, 0, 0);
                acc[ct] = __builtin_amdgcn_mfma_f32_16x16x32_bf16(ah, bl, acc[ct], 0, 0, 0);
                acc[ct] = __builtin_amdgcn_mfma_f32_16x16x32_bf16(al, bh, acc[ct], 0, 0, 0);
            }
        }
    }

    #pragma unroll
    for (int ct = 0; ct < NT; ct++) {
        #pragma unroll
        for (int r = 0; r < 4; r++) {
            int row = node0 + w * 16 + kgrp * 4 + r;
            int col = ct * 16 + ln16;
            out[(size_t)row * NOUT + col] = fmaxf(acc[ct][r], 0.f);
        }
    }
}

// ---------------- final FC (no relu): logits = h2 @ Wfc + bfc ----------------

__global__ void fc_k(const float* __restrict__ h2, const float* __restrict__ W,
                     const float* __restrict__ b, float* __restrict__ out) {
    int idx = blockIdx.x * blockDim.x + threadIdx.x;
    if (idx >= N_NODES * D_OUT) return;
    int node = idx / D_OUT;
    int c = idx - node * D_OUT;
    float acc = b[c];
    const float4* h4 = (const float4*)(h2 + (size_t)node * D_H2);
    #pragma unroll
    for (int k4 = 0; k4 < D_H2 / 4; k4++) {
        float4 h = h4[k4];
        acc += h.x * W[(k4 * 4 + 0) * D_OUT + c];
        acc += h.y * W[(k4 * 4 + 1) * D_OUT + c];
        acc += h.z * W[(k4 * 4 + 2) * D_OUT + c];
        acc += h.w * W[(k4 * 4 + 3) * D_OUT + c];
    }
    out[idx] = acc;
}

// ---------------- launch ----------------

extern "C" void kernel_launch(void* const* d_in, const int* in_sizes, int n_in,
                              void* d_out, int out_size, void* d_ws, size_t ws_size,
                              hipStream_t stream) {
    const float* x       = (const float*)d_in[0];
    const int*   ei      = (const int*)d_in[1];
    const float* W1_nb   = (const float*)d_in[2];
    const float* b1      = (const float*)d_in[3];
    const float* W1_self = (const float*)d_in[4];
    const float* W2_nb   = (const float*)d_in[5];
    const float* b2      = (const float*)d_in[6];
    const float* W2_self = (const float*)d_in[7];
    const float* Wfc     = (const float*)d_in[8];
    const float* bfc     = (const float*)d_in[9];

    const int* src = ei;            // edge_index[0]
    const int* dst = ei + N_EDGES;  // edge_index[1]

    // workspace layout
    char* w = (char*)d_ws;
    int* deg        = (int*)w;                         // N
    int* offsets    = deg + N_NODES;                   // N+1
    int* cursor     = offsets + (N_NODES + 1);         // N
    int* blocksum   = cursor + N_NODES;                // 40
    int* blockbase  = blocksum + N_SCAN_BLKS;          // 40
    int* src_sorted = blockbase + N_SCAN_BLKS;         // E
    size_t int_elems = (size_t)N_NODES * 3 + 1 + 2 * N_SCAN_BLKS + N_EDGES;
    size_t int_bytes = (int_elems * 4 + 15) & ~(size_t)15;
    float* mean = (float*)(w + int_bytes);             // N*128 (reused layer 2)
    float* h1   = mean + (size_t)N_NODES * 128;        // N*128
    short* w1nb_h   = (short*)(h1 + (size_t)N_NODES * 128);
    short* w1nb_l   = w1nb_h + 128 * 128;
    short* w1self_h = w1nb_l + 128 * 128;
    short* w1self_l = w1self_h + 128 * 128;
    short* w2nb_h   = w1self_l + 128 * 128;
    short* w2nb_l   = w2nb_h + 128 * 64;
    short* w2self_h = w2nb_l + 128 * 64;
    short* w2self_l = w2self_h + 128 * 64;

    float* emb    = (float*)d_out;                     // [N, 64]
    float* logits = emb + (size_t)N_NODES * D_H2;      // [N, 40]

    // 0. weight split/transpose (tiny; L1/L2-resident afterwards)
    wsplit_k<<<(128 * 128 + 255) / 256, 256, 0, stream>>>(W1_nb,   128, 128, w1nb_h,   w1nb_l);
    wsplit_k<<<(128 * 128 + 255) / 256, 256, 0, stream>>>(W1_self, 128, 128, w1self_h, w1self_l);
    wsplit_k<<<(128 * 64  + 255) / 256, 256, 0, stream>>>(W2_nb,   128, 64,  w2nb_h,   w2nb_l);
    wsplit_k<<<(128 * 64  + 255) / 256, 256, 0, stream>>>(W2_self, 128, 64,  w2self_h, w2self_l);

    // 1. CSR build (shared by both layers)
    hipMemsetAsync(deg, 0, N_NODES * sizeof(int), stream);
    hist_k<<<(N_EDGES + 255) / 256, 256, 0, stream>>>(dst, deg);
    scan1_k<<<N_SCAN_BLKS, SCAN_BLK, 0, stream>>>(deg, blocksum);
    scan2_k<<<1, 64, 0, stream>>>(blocksum, blockbase, offsets);
    scan3_k<<<N_SCAN_BLKS, SCAN_BLK, 0, stream>>>(deg, blockbase, offsets, cursor);
    place_k<<<(N_EDGES + 255) / 256, 256, 0, stream>>>(src, dst, cursor, src_sorted);

    // 2. layer 1
    agg_k<<<N_NODES / 8, 256, 0, stream>>>(x, offsets, src_sorted, mean);
    sage_mfma_k<128><<<N_NODES / 64, 256, 0, stream>>>(mean, x, w1nb_h, w1nb_l,
                                                       w1self_h, w1self_l, b1, h1);

    // 3. layer 2 (reuse mean buffer)
    agg_k<<<N_NODES / 8, 256, 0, stream>>>(h1, offsets, src_sorted, mean);
    sage_mfma_k<64><<<N_NODES / 64, 256, 0, stream>>>(mean, h1, w2nb_h, w2nb_l,
                                                      w2self_h, w2self_l, b2, emb);

    // 4. FC head
    fc_k<<<(N_NODES * D_OUT + 255) / 256, 256, 0, stream>>>(emb, Wfc, bfc, logits);
}

// Round 6
// 322.849 us; speedup vs baseline: 1.4141x; 1.1175x over previous
//
#include <hip/hip_runtime.h>
#include <hip/hip_bf16.h>

// GraphSAGE forward: 2x SAGEConv(mean) + ReLU, then FC.
// N=40000 nodes, E=640000 edges, dims 128 -> 128 -> 64 -> 40.
// R6: GEMM restructured — W staged in LDS (XOR-swizzled, read-only inner loop),
// A fragments global->reg with per-thread hi/lo split; 32x64 tiles, col-split
// grid (2500 blocks for gemm128). Inner loop = ds_read_b128 + MFMA only.

#define N_NODES 40000
#define N_EDGES 640000
#define D_IN    128
#define D_H1    128
#define D_H2    64
#define D_OUT   40

#define SCAN_BLK 1024
#define N_SCAN_BLKS ((N_NODES + SCAN_BLK - 1) / SCAN_BLK)  // 40

typedef __attribute__((ext_vector_type(8))) short short8v;
typedef __attribute__((ext_vector_type(4))) float float4v;

__device__ __forceinline__ unsigned short f2bf(float f) {
    unsigned u = __float_as_uint(f);
    unsigned r = u + 0x7FFFu + ((u >> 16) & 1u);   // RNE
    return (unsigned short)(r >> 16);
}
__device__ __forceinline__ float bf2f(unsigned short b) {
    return __uint_as_float(((unsigned)b) << 16);
}

// ---------------- CSR build ----------------

__global__ void hist_k(const int* __restrict__ dst, int* __restrict__ deg) {
    int e = blockIdx.x * blockDim.x + threadIdx.x;
    if (e < N_EDGES) atomicAdd(&deg[dst[e]], 1);
}

__global__ __launch_bounds__(SCAN_BLK) void scan1_k(const int* __restrict__ deg,
                                                    int* __restrict__ blocksum) {
    __shared__ int wsum[SCAN_BLK / 64];
    int t = threadIdx.x;
    int i = blockIdx.x * SCAN_BLK + t;
    int v = (i < N_NODES) ? deg[i] : 0;
    #pragma unroll
    for (int s = 32; s > 0; s >>= 1) v += __shfl_down(v, s);
    if ((t & 63) == 0) wsum[t >> 6] = v;
    __syncthreads();
    if (t < SCAN_BLK / 64) {
        int x = wsum[t];
        #pragma unroll
        for (int s = SCAN_BLK / 128; s > 0; s >>= 1) x += __shfl_down(x, s);
        if (t == 0) blocksum[blockIdx.x] = x;
    }
}

__global__ void scan2_k(const int* __restrict__ blocksum, int* __restrict__ blockbase,
                        int* __restrict__ offsets) {
    if (threadIdx.x == 0 && blockIdx.x == 0) {
        int acc = 0;
        for (int b = 0; b < N_SCAN_BLKS; b++) { blockbase[b] = acc; acc += blocksum[b]; }
        offsets[N_NODES] = acc;
    }
}

__global__ __launch_bounds__(SCAN_BLK) void scan3_k(const int* __restrict__ deg,
                                                    const int* __restrict__ blockbase,
                                                    int* __restrict__ offsets,
                                                    int* __restrict__ cursor) {
    __shared__ int sm[SCAN_BLK];
    int t = threadIdx.x;
    int i = blockIdx.x * SCAN_BLK + t;
    int v = (i < N_NODES) ? deg[i] : 0;
    sm[t] = v;
    __syncthreads();
    for (int s = 1; s < SCAN_BLK; s <<= 1) {
        int u = (t >= s) ? sm[t - s] : 0;
        __syncthreads();
        sm[t] += u;
        __syncthreads();
    }
    if (i < N_NODES) {
        int excl = blockbase[blockIdx.x] + sm[t] - v;
        offsets[i] = excl;
        cursor[i] = excl;
    }
}

__global__ void place_k(const int* __restrict__ src, const int* __restrict__ dst,
                        int* __restrict__ cursor, int* __restrict__ src_sorted) {
    int e = blockIdx.x * blockDim.x + threadIdx.x;
    if (e < N_EDGES) {
        int p = atomicAdd(&cursor[dst[e]], 1);
        src_sorted[p] = src[e];
    }
}

// ---------------- mean aggregation (gather, float4) ----------------

__global__ __launch_bounds__(256) void agg_k(const float* __restrict__ feat,
                                             const int* __restrict__ offsets,
                                             const int* __restrict__ srcs,
                                             float* __restrict__ mean_out) {
    int t = threadIdx.x;
    int g = t >> 5;
    int q = t & 31;
    int node = blockIdx.x * 8 + g;
    int beg = offsets[node];
    int end = offsets[node + 1];
    float ax = 0.f, ay = 0.f, az = 0.f, aw = 0.f;
    int i = beg;
    for (; i + 4 <= end; i += 4) {
        int s0 = srcs[i], s1 = srcs[i + 1], s2 = srcs[i + 2], s3 = srcs[i + 3];
        float4 v0 = ((const float4*)(feat + (size_t)s0 * 128))[q];
        float4 v1 = ((const float4*)(feat + (size_t)s1 * 128))[q];
        float4 v2 = ((const float4*)(feat + (size_t)s2 * 128))[q];
        float4 v3 = ((const float4*)(feat + (size_t)s3 * 128))[q];
        ax += v0.x + v1.x + v2.x + v3.x;
        ay += v0.y + v1.y + v2.y + v3.y;
        az += v0.z + v1.z + v2.z + v3.z;
        aw += v0.w + v1.w + v2.w + v3.w;
    }
    for (; i < end; ++i) {
        float4 v = ((const float4*)(feat + (size_t)srcs[i] * 128))[q];
        ax += v.x; ay += v.y; az += v.z; aw += v.w;
    }
    int cnt = end - beg;
    float inv = 1.0f / (float)(cnt > 1 ? cnt : 1);
    float4 r; r.x = ax * inv; r.y = ay * inv; r.z = az * inv; r.w = aw * inv;
    ((float4*)(mean_out + (size_t)node * 128))[q] = r;
}

// ---------------- W split+transpose: W[K][N] fp32 -> Wt_hi/lo[N][K] bf16 ----------------

__global__ void wsplit_k(const float* __restrict__ W, int K, int N,
                         short* __restrict__ Wt_hi, short* __restrict__ Wt_lo) {
    int tid = blockIdx.x * blockDim.x + threadIdx.x;
    if (tid >= K * N) return;
    int k = tid / N, n = tid - k * N;
    float w = W[tid];
    unsigned short h = f2bf(w);
    unsigned short lo = f2bf(w - bf2f(h));
    Wt_hi[n * K + k] = (short)h;
    Wt_lo[n * K + k] = (short)lo;
}

// ---------------- fused dual GEMM via split-bf16 MFMA (v2) ----------------
// Block tile: 32 rows x 64 cols; grid = (M/32, NOUT/64). 4 waves:
//   wave w -> rows (w&1)*16, cols (w>>1)*32 within the block's 64-col slice.
// Per phase: W-slice (hi+lo, 32KB) staged to LDS with XOR swizzle; each lane's
// A-fragment rows read global->reg and split hi/lo ONCE, reused across col
// tiles. Inner loop is ds_read_b128 + MFMA only (no global loads).
// mfma_f32_16x16x32_bf16 layouts [guide-verified m89/m91]:
//   A-frag: row=lane&15, k=(lane>>4)*8+j ; B-frag: col=lane&15, same k
//   C/D   : col=lane&15, row=(lane>>4)*4+reg

template <int NOUT>
__global__ __launch_bounds__(256) void sage_mfma_k(
    const float* __restrict__ A1, const float* __restrict__ A2,
    const short* __restrict__ W1h, const short* __restrict__ W1l,
    const short* __restrict__ W2h, const short* __restrict__ W2l,
    const float* __restrict__ bias, float* __restrict__ out) {
    __shared__ short wh_s[64 * 128];   // 16KB [col][k], XOR-swizzled
    __shared__ short wl_s[64 * 128];   // 16KB

    const int t = threadIdx.x;
    const int w = t >> 6;
    const int l = t & 63;
    const int ln16 = l & 15;
    const int kgrp = l >> 4;                      // 0..3
    const int arow = blockIdx.x * 32 + (w & 1) * 16 + ln16;
    const int colbase = blockIdx.y * 64;          // block's col slice
    const int cw = (w >> 1) * 32;                 // wave's col offset in slice

    float4v acc[2];
    #pragma unroll
    for (int ct = 0; ct < 2; ct++) {
        float bv = bias[colbase + cw + ct * 16 + ln16];
        acc[ct] = (float4v){bv, bv, bv, bv};
    }

    for (int phase = 0; phase < 2; ++phase) {
        const float* __restrict__ A  = phase ? A2 : A1;
        const short* __restrict__ Wh = phase ? W2h : W1h;
        const short* __restrict__ Wl = phase ? W2l : W1l;

        __syncthreads();   // previous phase done reading LDS

        // issue A loads first (latency overlaps W staging below)
        float4 a0[4], a1[4];
        const float* ap = A + (size_t)arow * 128 + kgrp * 8;
        #pragma unroll
        for (int kc = 0; kc < 4; kc++) {
            a0[kc] = *(const float4*)(ap + kc * 32);
            a1[kc] = *(const float4*)(ap + kc * 32 + 4);
        }

        // stage W slice (64 cols x 128 k, hi+lo) into LDS, swizzled, coalesced
        #pragma unroll
        for (int it = 0; it < 4; it++) {
            int fid = t + it * 256;                // 1024 x 16B chunks per array
            int r = fid >> 4, c = fid & 15;
            int gofs = (colbase + r) * 128 + c * 8;
            int byte = (r * 256 + c * 16) ^ ((r & 7) << 4);
            *(int4*)((char*)wh_s + byte) = *(const int4*)(Wh + gofs);
            *(int4*)((char*)wl_s + byte) = *(const int4*)(Wl + gofs);
        }

        // split A fragments to hi/lo bf16 in registers (reused across ct)
        short8v ah[4], al[4];
        #pragma unroll
        for (int kc = 0; kc < 4; kc++) {
            #pragma unroll
            for (int j = 0; j < 4; j++) {
                float f0 = (&a0[kc].x)[j];
                float f1 = (&a1[kc].x)[j];
                unsigned short h0 = f2bf(f0), h1 = f2bf(f1);
                ah[kc][j]     = (short)h0;
                ah[kc][j + 4] = (short)h1;
                al[kc][j]     = (short)f2bf(f0 - bf2f(h0));
                al[kc][j + 4] = (short)f2bf(f1 - bf2f(h1));
            }
        }

        __syncthreads();   // W staged

        #pragma unroll
        for (int kc = 0; kc < 4; kc++) {
            #pragma unroll
            for (int ct = 0; ct < 2; ct++) {
                int col = cw + ct * 16 + ln16;
                int byte = (col * 256 + kc * 64 + kgrp * 16) ^ ((col & 7) << 4);
                short8v bh = *(const short8v*)((const char*)wh_s + byte);
                short8v bl = *(const short8v*)((const char*)wl_s + byte);
                acc[ct] = __builtin_amdgcn_mfma_f32_16x16x32_bf16(ah[kc], bh, acc[ct], 0, 0, 0);
                acc[ct] = __builtin_amdgcn_mfma_f32_16x16x32_bf16(ah[kc], bl, acc[ct], 0, 0, 0);
                acc[ct] = __builtin_amdgcn_mfma_f32_16x16x32_bf16(al[kc], bh, acc[ct], 0, 0, 0);
            }
        }
    }

    #pragma unroll
    for (int ct = 0; ct < 2; ct++) {
        #pragma unroll
        for (int r = 0; r < 4; r++) {
            int row = blockIdx.x * 32 + (w & 1) * 16 + kgrp * 4 + r;
            int col = colbase + cw + ct * 16 + ln16;
            out[(size_t)row * NOUT + col] = fmaxf(acc[ct][r], 0.f);
        }
    }
}

// ---------------- final FC (no relu): logits = h2 @ Wfc + bfc ----------------

__global__ void fc_k(const float* __restrict__ h2, const float* __restrict__ W,
                     const float* __restrict__ b, float* __restrict__ out) {
    int idx = blockIdx.x * blockDim.x + threadIdx.x;
    if (idx >= N_NODES * D_OUT) return;
    int node = idx / D_OUT;
    int c = idx - node * D_OUT;
    float acc = b[c];
    const float4* h4 = (const float4*)(h2 + (size_t)node * D_H2);
    #pragma unroll
    for (int k4 = 0; k4 < D_H2 / 4; k4++) {
        float4 h = h4[k4];
        acc += h.x * W[(k4 * 4 + 0) * D_OUT + c];
        acc += h.y * W[(k4 * 4 + 1) * D_OUT + c];
        acc += h.z * W[(k4 * 4 + 2) * D_OUT + c];
        acc += h.w * W[(k4 * 4 + 3) * D_OUT + c];
    }
    out[idx] = acc;
}

// ---------------- launch ----------------

extern "C" void kernel_launch(void* const* d_in, const int* in_sizes, int n_in,
                              void* d_out, int out_size, void* d_ws, size_t ws_size,
                              hipStream_t stream) {
    const float* x       = (const float*)d_in[0];
    const int*   ei      = (const int*)d_in[1];
    const float* W1_nb   = (const float*)d_in[2];
    const float* b1      = (const float*)d_in[3];
    const float* W1_self = (const float*)d_in[4];
    const float* W2_nb   = (const float*)d_in[5];
    const float* b2      = (const float*)d_in[6];
    const float* W2_self = (const float*)d_in[7];
    const float* Wfc     = (const float*)d_in[8];
    const float* bfc     = (const float*)d_in[9];

    const int* src = ei;            // edge_index[0]
    const int* dst = ei + N_EDGES;  // edge_index[1]

    // workspace layout
    char* w = (char*)d_ws;
    int* deg        = (int*)w;                         // N
    int* offsets    = deg + N_NODES;                   // N+1
    int* cursor     = offsets + (N_NODES + 1);         // N
    int* blocksum   = cursor + N_NODES;                // 40
    int* blockbase  = blocksum + N_SCAN_BLKS;          // 40
    int* src_sorted = blockbase + N_SCAN_BLKS;         // E
    size_t int_elems = (size_t)N_NODES * 3 + 1 + 2 * N_SCAN_BLKS + N_EDGES;
    size_t int_bytes = (int_elems * 4 + 15) & ~(size_t)15;
    float* mean = (float*)(w + int_bytes);             // N*128 (reused layer 2)
    float* h1   = mean + (size_t)N_NODES * 128;        // N*128
    short* w1nb_h   = (short*)(h1 + (size_t)N_NODES * 128);
    short* w1nb_l   = w1nb_h + 128 * 128;
    short* w1self_h = w1nb_l + 128 * 128;
    short* w1self_l = w1self_h + 128 * 128;
    short* w2nb_h   = w1self_l + 128 * 128;
    short* w2nb_l   = w2nb_h + 128 * 64;
    short* w2self_h = w2nb_l + 128 * 64;
    short* w2self_l = w2self_h + 128 * 64;

    float* emb    = (float*)d_out;                     // [N, 64]
    float* logits = emb + (size_t)N_NODES * D_H2;      // [N, 40]

    // 0. weight split/transpose (tiny; L1/L2-resident afterwards)
    wsplit_k<<<(128 * 128 + 255) / 256, 256, 0, stream>>>(W1_nb,   128, 128, w1nb_h,   w1nb_l);
    wsplit_k<<<(128 * 128 + 255) / 256, 256, 0, stream>>>(W1_self, 128, 128, w1self_h, w1self_l);
    wsplit_k<<<(128 * 64  + 255) / 256, 256, 0, stream>>>(W2_nb,   128, 64,  w2nb_h,   w2nb_l);
    wsplit_k<<<(128 * 64  + 255) / 256, 256, 0, stream>>>(W2_self, 128, 64,  w2self_h, w2self_l);

    // 1. CSR build (shared by both layers)
    hipMemsetAsync(deg, 0, N_NODES * sizeof(int), stream);
    hist_k<<<(N_EDGES + 255) / 256, 256, 0, stream>>>(dst, deg);
    scan1_k<<<N_SCAN_BLKS, SCAN_BLK, 0, stream>>>(deg, blocksum);
    scan2_k<<<1, 64, 0, stream>>>(blocksum, blockbase, offsets);
    scan3_k<<<N_SCAN_BLKS, SCAN_BLK, 0, stream>>>(deg, blockbase, offsets, cursor);
    place_k<<<(N_EDGES + 255) / 256, 256, 0, stream>>>(src, dst, cursor, src_sorted);

    // 2. layer 1
    agg_k<<<N_NODES / 8, 256, 0, stream>>>(x, offsets, src_sorted, mean);
    sage_mfma_k<128><<<dim3(N_NODES / 32, 2), 256, 0, stream>>>(mean, x, w1nb_h, w1nb_l,
                                                                w1self_h, w1self_l, b1, h1);

    // 3. layer 2 (reuse mean buffer)
    agg_k<<<N_NODES / 8, 256, 0, stream>>>(h1, offsets, src_sorted, mean);
    sage_mfma_k<64><<<dim3(N_NODES / 32, 1), 256, 0, stream>>>(mean, h1, w2nb_h, w2nb_l,
                                                               w2self_h, w2self_l, b2, emb);

    // 4. FC head
    fc_k<<<(N_NODES * D_OUT + 255) / 256, 256, 0, stream>>>(emb, Wfc, bfc, logits);
}

// Round 8
// 293.982 us; speedup vs baseline: 1.5529x; 1.0982x over previous
//
#include <hip/hip_runtime.h>
#include <hip/hip_bf16.h>

// GraphSAGE forward: 2x SAGEConv(mean) + ReLU, then FC.
// R7 (resubmitted in R8; prior round hit GPU acquisition timeout):
// linearity trick — layer-2 aggregation moved AFTER the W2 transform
// (agg(h1)@W2nb == agg(h1@W2nb)), halving layer-2 gather bytes (128->64 dims).
// gemm2p computes zs2 = h1@[W2nb | W2self]+[0|b2]; final_k fuses
// relu(mean2+s2) epilogue with the 64x40 FC head. agg unrolled 8-deep.
// Kernel count 14 -> 11 (wsplit merged, scan2 folded into scan3).

#define N_NODES 40000
#define N_EDGES 640000
#define D_IN    128
#define D_H1    128
#define D_H2    64
#define D_OUT   40

#define SCAN_BLK 1024
#define N_SCAN_BLKS ((N_NODES + SCAN_BLK - 1) / SCAN_BLK)  // 40

typedef __attribute__((ext_vector_type(8))) short short8v;
typedef __attribute__((ext_vector_type(4))) float float4v;

__device__ __forceinline__ unsigned short f2bf(float f) {
    unsigned u = __float_as_uint(f);
    unsigned r = u + 0x7FFFu + ((u >> 16) & 1u);   // RNE
    return (unsigned short)(r >> 16);
}
__device__ __forceinline__ float bf2f(unsigned short b) {
    return __uint_as_float(((unsigned)b) << 16);
}

// ---------------- CSR build ----------------

__global__ void hist_k(const int* __restrict__ dst, int* __restrict__ deg) {
    int e = blockIdx.x * blockDim.x + threadIdx.x;
    if (e < N_EDGES) atomicAdd(&deg[dst[e]], 1);
}

__global__ __launch_bounds__(SCAN_BLK) void scan1_k(const int* __restrict__ deg,
                                                    int* __restrict__ blocksum) {
    __shared__ int wsum[SCAN_BLK / 64];
    int t = threadIdx.x;
    int i = blockIdx.x * SCAN_BLK + t;
    int v = (i < N_NODES) ? deg[i] : 0;
    #pragma unroll
    for (int s = 32; s > 0; s >>= 1) v += __shfl_down(v, s);
    if ((t & 63) == 0) wsum[t >> 6] = v;
    __syncthreads();
    if (t < SCAN_BLK / 64) {
        int x = wsum[t];
        #pragma unroll
        for (int s = SCAN_BLK / 128; s > 0; s >>= 1) x += __shfl_down(x, s);
        if (t == 0) blocksum[blockIdx.x] = x;
    }
}

// block-local exclusive scan + serial base over 40 blocksums (scan2 folded in)
__global__ __launch_bounds__(SCAN_BLK) void scan3_k(const int* __restrict__ deg,
                                                    const int* __restrict__ blocksum,
                                                    int* __restrict__ offsets,
                                                    int* __restrict__ cursor) {
    __shared__ int sm[SCAN_BLK];
    __shared__ int base_s;
    int t = threadIdx.x;
    int i = blockIdx.x * SCAN_BLK + t;
    if (t == 0) {
        int b = 0;
        for (int j = 0; j < (int)blockIdx.x; j++) b += blocksum[j];
        base_s = b;
        if (blockIdx.x == N_SCAN_BLKS - 1)
            offsets[N_NODES] = b + blocksum[blockIdx.x];
    }
    int v = (i < N_NODES) ? deg[i] : 0;
    sm[t] = v;
    __syncthreads();
    for (int s = 1; s < SCAN_BLK; s <<= 1) {
        int u = (t >= s) ? sm[t - s] : 0;
        __syncthreads();
        sm[t] += u;
        __syncthreads();
    }
    if (i < N_NODES) {
        int excl = base_s + sm[t] - v;
        offsets[i] = excl;
        cursor[i] = excl;
    }
}

__global__ void place_k(const int* __restrict__ src, const int* __restrict__ dst,
                        int* __restrict__ cursor, int* __restrict__ src_sorted) {
    int e = blockIdx.x * blockDim.x + threadIdx.x;
    if (e < N_EDGES) {
        int p = atomicAdd(&cursor[dst[e]], 1);
        src_sorted[p] = src[e];
    }
}

// ---------------- mean aggregation (gather, float4, unroll-8) ----------------
// D floats gathered per row (rows have STRIDE floats); 256/(D/4) nodes per block.

template <int D, int STRIDE>
__global__ __launch_bounds__(256) void agg_k(const float* __restrict__ feat,
                                             const int* __restrict__ offsets,
                                             const int* __restrict__ srcs,
                                             float* __restrict__ mean_out) {
    constexpr int LPN = D / 4;          // lanes per node (32 or 16)
    constexpr int NPB = 256 / LPN;      // nodes per block (8 or 16)
    int t = threadIdx.x;
    int g = t / LPN;
    int q = t % LPN;
    int node = blockIdx.x * NPB + g;
    int beg = offsets[node];
    int end = offsets[node + 1];
    float4 accA = {0.f, 0.f, 0.f, 0.f}, accB = {0.f, 0.f, 0.f, 0.f};
    int i = beg;
    for (; i + 8 <= end; i += 8) {
        float4 v[8];
        #pragma unroll
        for (int j = 0; j < 8; j++) {
            int s = srcs[i + j];
            v[j] = *(const float4*)(feat + (size_t)s * STRIDE + q * 4);
        }
        #pragma unroll
        for (int j = 0; j < 4; j++) {
            accA.x += v[j].x; accA.y += v[j].y; accA.z += v[j].z; accA.w += v[j].w;
            accB.x += v[j+4].x; accB.y += v[j+4].y; accB.z += v[j+4].z; accB.w += v[j+4].w;
        }
    }
    for (; i < end; ++i) {
        float4 v = *(const float4*)(feat + (size_t)srcs[i] * STRIDE + q * 4);
        accA.x += v.x; accA.y += v.y; accA.z += v.z; accA.w += v.w;
    }
    int cnt = end - beg;
    float inv = 1.0f / (float)(cnt > 1 ? cnt : 1);
    float4 r;
    r.x = (accA.x + accB.x) * inv; r.y = (accA.y + accB.y) * inv;
    r.z = (accA.z + accB.z) * inv; r.w = (accA.w + accB.w) * inv;
    *(float4*)(mean_out + (size_t)node * D + q * 4) = r;
}

// ---------------- W split+transpose (all four weights, one launch) ----------------
// W[K][N] fp32 -> Wt_hi/lo[N][K] bf16.

__device__ __forceinline__ void wsplit_one(const float* W, int K, int N, int tid,
                                           short* Wt_hi, short* Wt_lo) {
    int k = tid / N, n = tid - k * N;
    float w = W[tid];
    unsigned short h = f2bf(w);
    unsigned short lo = f2bf(w - bf2f(h));
    Wt_hi[n * K + k] = (short)h;
    Wt_lo[n * K + k] = (short)lo;
}

__global__ void wsplit_all_k(const float* __restrict__ W1nb, const float* __restrict__ W1sf,
                             const float* __restrict__ W2nb, const float* __restrict__ W2sf,
                             short* __restrict__ o1nbh, short* __restrict__ o1nbl,
                             short* __restrict__ o1sfh, short* __restrict__ o1sfl,
                             short* __restrict__ o2nbh, short* __restrict__ o2nbl,
                             short* __restrict__ o2sfh, short* __restrict__ o2sfl) {
    int tid = blockIdx.x * blockDim.x + threadIdx.x;
    if (tid < 16384)      wsplit_one(W1nb, 128, 128, tid,          o1nbh, o1nbl);
    else if (tid < 32768) wsplit_one(W1sf, 128, 128, tid - 16384,  o1sfh, o1sfl);
    else if (tid < 40960) wsplit_one(W2nb, 128, 64,  tid - 32768,  o2nbh, o2nbl);
    else if (tid < 49152) wsplit_one(W2sf, 128, 64,  tid - 40960,  o2sfh, o2sfl);
}

// ---------------- layer-1 fused dual GEMM (unchanged from R6) ----------------
// h1[32x64 tile] = relu(mean1@W1nb + x@W1self + b1); grid (1250, 2).

template <int NOUT>
__global__ __launch_bounds__(256) void sage_mfma_k(
    const float* __restrict__ A1, const float* __restrict__ A2,
    const short* __restrict__ W1h, const short* __restrict__ W1l,
    const short* __restrict__ W2h, const short* __restrict__ W2l,
    const float* __restrict__ bias, float* __restrict__ out) {
    __shared__ short wh_s[64 * 128];
    __shared__ short wl_s[64 * 128];

    const int t = threadIdx.x;
    const int w = t >> 6;
    const int l = t & 63;
    const int ln16 = l & 15;
    const int kgrp = l >> 4;
    const int arow = blockIdx.x * 32 + (w & 1) * 16 + ln16;
    const int colbase = blockIdx.y * 64;
    const int cw = (w >> 1) * 32;

    float4v acc[2];
    #pragma unroll
    for (int ct = 0; ct < 2; ct++) {
        float bv = bias[colbase + cw + ct * 16 + ln16];
        acc[ct] = (float4v){bv, bv, bv, bv};
    }

    for (int phase = 0; phase < 2; ++phase) {
        const float* __restrict__ A  = phase ? A2 : A1;
        const short* __restrict__ Wh = phase ? W2h : W1h;
        const short* __restrict__ Wl = phase ? W2l : W1l;

        __syncthreads();

        float4 a0[4], a1[4];
        const float* ap = A + (size_t)arow * 128 + kgrp * 8;
        #pragma unroll
        for (int kc = 0; kc < 4; kc++) {
            a0[kc] = *(const float4*)(ap + kc * 32);
            a1[kc] = *(const float4*)(ap + kc * 32 + 4);
        }

        #pragma unroll
        for (int it = 0; it < 4; it++) {
            int fid = t + it * 256;
            int r = fid >> 4, c = fid & 15;
            int gofs = (colbase + r) * 128 + c * 8;
            int byte = (r * 256 + c * 16) ^ ((r & 7) << 4);
            *(int4*)((char*)wh_s + byte) = *(const int4*)(Wh + gofs);
            *(int4*)((char*)wl_s + byte) = *(const int4*)(Wl + gofs);
        }

        short8v ah[4], al[4];
        #pragma unroll
        for (int kc = 0; kc < 4; kc++) {
            #pragma unroll
            for (int j = 0; j < 4; j++) {
                float f0 = (&a0[kc].x)[j];
                float f1 = (&a1[kc].x)[j];
                unsigned short h0 = f2bf(f0), h1 = f2bf(f1);
                ah[kc][j]     = (short)h0;
                ah[kc][j + 4] = (short)h1;
                al[kc][j]     = (short)f2bf(f0 - bf2f(h0));
                al[kc][j + 4] = (short)f2bf(f1 - bf2f(h1));
            }
        }

        __syncthreads();

        #pragma unroll
        for (int kc = 0; kc < 4; kc++) {
            #pragma unroll
            for (int ct = 0; ct < 2; ct++) {
                int col = cw + ct * 16 + ln16;
                int byte = (col * 256 + kc * 64 + kgrp * 16) ^ ((col & 7) << 4);
                short8v bh = *(const short8v*)((const char*)wh_s + byte);
                short8v bl = *(const short8v*)((const char*)wl_s + byte);
                acc[ct] = __builtin_amdgcn_mfma_f32_16x16x32_bf16(ah[kc], bh, acc[ct], 0, 0, 0);
                acc[ct] = __builtin_amdgcn_mfma_f32_16x16x32_bf16(ah[kc], bl, acc[ct], 0, 0, 0);
                acc[ct] = __builtin_amdgcn_mfma_f32_16x16x32_bf16(al[kc], bh, acc[ct], 0, 0, 0);
            }
        }
    }

    #pragma unroll
    for (int ct = 0; ct < 2; ct++) {
        #pragma unroll
        for (int r = 0; r < 4; r++) {
            int row = blockIdx.x * 32 + (w & 1) * 16 + kgrp * 4 + r;
            int col = colbase + cw + ct * 16 + ln16;
            out[(size_t)row * NOUT + col] = fmaxf(acc[ct][r], 0.f);
        }
    }
}

// ---------------- layer-2 pre-transform GEMM ----------------
// zs2[40000,128]: cols 0-63 = h1@W2nb (no bias, no relu); cols 64-127 = h1@W2self + b2.
// grid (1250, 2): blockIdx.y selects which W. Single K=128 phase.

__global__ __launch_bounds__(256) void gemm2_k(
    const float* __restrict__ A,
    const short* __restrict__ Wnbh, const short* __restrict__ Wnbl,
    const short* __restrict__ Wsfh, const short* __restrict__ Wsfl,
    const float* __restrict__ b2, float* __restrict__ zs2) {
    __shared__ short wh_s[64 * 128];
    __shared__ short wl_s[64 * 128];

    const int t = threadIdx.x;
    const int w = t >> 6;
    const int l = t & 63;
    const int ln16 = l & 15;
    const int kgrp = l >> 4;
    const int arow = blockIdx.x * 32 + (w & 1) * 16 + ln16;
    const int ysel = blockIdx.y;          // 0: nb, 1: self(+b2)
    const int cw = (w >> 1) * 32;

    const short* __restrict__ Wh = ysel ? Wsfh : Wnbh;
    const short* __restrict__ Wl = ysel ? Wsfl : Wnbl;

    float4v acc[2];
    #pragma unroll
    for (int ct = 0; ct < 2; ct++) {
        float bv = ysel ? b2[cw + ct * 16 + ln16] : 0.f;
        acc[ct] = (float4v){bv, bv, bv, bv};
    }

    float4 a0[4], a1[4];
    const float* ap = A + (size_t)arow * 128 + kgrp * 8;
    #pragma unroll
    for (int kc = 0; kc < 4; kc++) {
        a0[kc] = *(const float4*)(ap + kc * 32);
        a1[kc] = *(const float4*)(ap + kc * 32 + 4);
    }

    #pragma unroll
    for (int it = 0; it < 4; it++) {
        int fid = t + it * 256;
        int r = fid >> 4, c = fid & 15;
        int gofs = r * 128 + c * 8;
        int byte = (r * 256 + c * 16) ^ ((r & 7) << 4);
        *(int4*)((char*)wh_s + byte) = *(const int4*)(Wh + gofs);
        *(int4*)((char*)wl_s + byte) = *(const int4*)(Wl + gofs);
    }

    short8v ah[4], al[4];
    #pragma unroll
    for (int kc = 0; kc < 4; kc++) {
        #pragma unroll
        for (int j = 0; j < 4; j++) {
            float f0 = (&a0[kc].x)[j];
            float f1 = (&a1[kc].x)[j];
            unsigned short h0 = f2bf(f0), h1 = f2bf(f1);
            ah[kc][j]     = (short)h0;
            ah[kc][j + 4] = (short)h1;
            al[kc][j]     = (short)f2bf(f0 - bf2f(h0));
            al[kc][j + 4] = (short)f2bf(f1 - bf2f(h1));
        }
    }

    __syncthreads();

    #pragma unroll
    for (int kc = 0; kc < 4; kc++) {
        #pragma unroll
        for (int ct = 0; ct < 2; ct++) {
            int col = cw + ct * 16 + ln16;
            int byte = (col * 256 + kc * 64 + kgrp * 16) ^ ((col & 7) << 4);
            short8v bh = *(const short8v*)((const char*)wh_s + byte);
            short8v bl = *(const short8v*)((const char*)wl_s + byte);
            acc[ct] = __builtin_amdgcn_mfma_f32_16x16x32_bf16(ah[kc], bh, acc[ct], 0, 0, 0);
            acc[ct] = __builtin_amdgcn_mfma_f32_16x16x32_bf16(ah[kc], bl, acc[ct], 0, 0, 0);
            acc[ct] = __builtin_amdgcn_mfma_f32_16x16x32_bf16(al[kc], bh, acc[ct], 0, 0, 0);
        }
    }

    #pragma unroll
    for (int ct = 0; ct < 2; ct++) {
        #pragma unroll
        for (int r = 0; r < 4; r++) {
            int row = blockIdx.x * 32 + (w & 1) * 16 + kgrp * 4 + r;
            int col = ysel * 64 + cw + ct * 16 + ln16;
            zs2[(size_t)row * 128 + col] = acc[ct][r];
        }
    }
}

// ---------------- final: emb = relu(mean2 + s2); logits = emb@Wfc + bfc ----------------
// 16 nodes per 256-thread block; emb staged in LDS (pad 68) for the FC dot.

__global__ __launch_bounds__(256) void final_k(const float* __restrict__ mean2,
                                               const float* __restrict__ zs2,
                                               const float* __restrict__ Wfc,
                                               const float* __restrict__ bfc,
                                               float* __restrict__ emb,
                                               float* __restrict__ logits) {
    __shared__ float es[16][68];
    int t = threadIdx.x;
    int g = t >> 4;
    int q = t & 15;
    int node = blockIdx.x * 16 + g;
    float4 m = *(const float4*)(mean2 + (size_t)node * 64 + q * 4);
    float4 s = *(const float4*)(zs2 + (size_t)node * 128 + 64 + q * 4);
    float4 e;
    e.x = fmaxf(m.x + s.x, 0.f);
    e.y = fmaxf(m.y + s.y, 0.f);
    e.z = fmaxf(m.z + s.z, 0.f);
    e.w = fmaxf(m.w + s.w, 0.f);
    *(float4*)(emb + (size_t)node * 64 + q * 4) = e;
    *(float4*)&es[g][q * 4] = e;
    __syncthreads();
    #pragma unroll
    for (int j = 0; j < 3; j++) {
        int c = q + 16 * j;
        if (c < D_OUT) {
            float acc = bfc[c];
            #pragma unroll
            for (int k = 0; k < 64; k++) acc += es[g][k] * Wfc[k * D_OUT + c];
            logits[(size_t)node * D_OUT + c] = acc;
        }
    }
}

// ---------------- launch ----------------

extern "C" void kernel_launch(void* const* d_in, const int* in_sizes, int n_in,
                              void* d_out, int out_size, void* d_ws, size_t ws_size,
                              hipStream_t stream) {
    const float* x       = (const float*)d_in[0];
    const int*   ei      = (const int*)d_in[1];
    const float* W1_nb   = (const float*)d_in[2];
    const float* b1      = (const float*)d_in[3];
    const float* W1_self = (const float*)d_in[4];
    const float* W2_nb   = (const float*)d_in[5];
    const float* b2      = (const float*)d_in[6];
    const float* W2_self = (const float*)d_in[7];
    const float* Wfc     = (const float*)d_in[8];
    const float* bfc     = (const float*)d_in[9];

    const int* src = ei;
    const int* dst = ei + N_EDGES;

    // workspace layout (bufA/bufB each reused twice — see timeline comments)
    char* w = (char*)d_ws;
    int* deg        = (int*)w;                         // N
    int* offsets    = deg + N_NODES;                   // N+1
    int* cursor     = offsets + (N_NODES + 1);         // N
    int* blocksum   = cursor + N_NODES;                // 40
    int* src_sorted = blocksum + N_SCAN_BLKS;          // E
    size_t int_elems = (size_t)N_NODES * 3 + 1 + N_SCAN_BLKS + N_EDGES;
    size_t int_bytes = (int_elems * 4 + 15) & ~(size_t)15;
    float* bufA = (float*)(w + int_bytes);             // N*128: mean1, then zs2
    float* bufB = bufA + (size_t)N_NODES * 128;        // N*128: h1, then mean2
    short* w1nb_h   = (short*)(bufB + (size_t)N_NODES * 128);
    short* w1nb_l   = w1nb_h + 128 * 128;
    short* w1self_h = w1nb_l + 128 * 128;
    short* w1self_l = w1self_h + 128 * 128;
    short* w2nb_h   = w1self_l + 128 * 128;
    short* w2nb_l   = w2nb_h + 128 * 64;
    short* w2self_h = w2nb_l + 128 * 64;
    short* w2self_l = w2self_h + 128 * 64;

    float* emb    = (float*)d_out;                     // [N, 64]
    float* logits = emb + (size_t)N_NODES * D_H2;      // [N, 40]

    // 0. weight split/transpose (single launch)
    wsplit_all_k<<<(49152 + 255) / 256, 256, 0, stream>>>(
        W1_nb, W1_self, W2_nb, W2_self,
        w1nb_h, w1nb_l, w1self_h, w1self_l, w2nb_h, w2nb_l, w2self_h, w2self_l);

    // 1. CSR build
    hipMemsetAsync(deg, 0, N_NODES * sizeof(int), stream);
    hist_k<<<(N_EDGES + 255) / 256, 256, 0, stream>>>(dst, deg);
    scan1_k<<<N_SCAN_BLKS, SCAN_BLK, 0, stream>>>(deg, blocksum);
    scan3_k<<<N_SCAN_BLKS, SCAN_BLK, 0, stream>>>(deg, blocksum, offsets, cursor);
    place_k<<<(N_EDGES + 255) / 256, 256, 0, stream>>>(src, dst, cursor, src_sorted);

    // 2. layer 1: mean1 = agg(x); h1 = relu(mean1@W1nb + x@W1self + b1)
    agg_k<128, 128><<<N_NODES / 8, 256, 0, stream>>>(x, offsets, src_sorted, bufA);
    sage_mfma_k<128><<<dim3(N_NODES / 32, 2), 256, 0, stream>>>(
        bufA, x, w1nb_h, w1nb_l, w1self_h, w1self_l, b1, bufB);

    // 3. layer 2 pre-transform: zs2 = h1@[W2nb | W2self+b2]  (bufB=h1 -> bufA=zs2)
    gemm2_k<<<dim3(N_NODES / 32, 2), 256, 0, stream>>>(
        bufB, w2nb_h, w2nb_l, w2self_h, w2self_l, b2, bufA);

    // 4. layer-2 aggregation on 64-dim transformed rows (bufA cols 0-63 -> bufB)
    agg_k<64, 128><<<N_NODES / 16, 256, 0, stream>>>(bufA, offsets, src_sorted, bufB);

    // 5. emb = relu(mean2 + s2); logits = emb@Wfc + bfc
    final_k<<<N_NODES / 16, 256, 0, stream>>>(bufB, bufA, Wfc, bfc, emb, logits);
}

// Round 13
// 264.129 us; speedup vs baseline: 1.7285x; 1.1130x over previous
//
#include <hip/hip_runtime.h>
#include <hip/hip_bf16.h>
#include <hip/hip_fp16.h>

// GraphSAGE forward: 2x SAGEConv(mean) + ReLU, then FC.
// R13 = R9 bundle with workspace overlay fix. R9-R11 hit acquisition timeouts;
// R12 hit "container failed twice" — possibly an OOB workspace write (R9 grew
// ws to 54.5MB vs proven 44.2MB). Fix: xh overlays the h1 region (xh is dead
// before h1's first write; stream-ordered). Compute graph unchanged:
// fp16 gather payloads (agg1 256B/edge, agg2 128B/edge via fp16 z2nb),
// agg2+epilogue+FC fused. Footprint back to 44.2MB.

#define N_NODES 40000
#define N_EDGES 640000
#define D_IN    128
#define D_H1    128
#define D_H2    64
#define D_OUT   40

#define SCAN_BLK 1024
#define N_SCAN_BLKS ((N_NODES + SCAN_BLK - 1) / SCAN_BLK)  // 40

typedef __attribute__((ext_vector_type(8))) short short8v;
typedef __attribute__((ext_vector_type(8))) _Float16 half8v;
typedef __attribute__((ext_vector_type(4))) float float4v;

__device__ __forceinline__ unsigned short f2bf(float f) {
    unsigned u = __float_as_uint(f);
    unsigned r = u + 0x7FFFu + ((u >> 16) & 1u);   // RNE
    return (unsigned short)(r >> 16);
}
__device__ __forceinline__ float bf2f(unsigned short b) {
    return __uint_as_float(((unsigned)b) << 16);
}

// ---------------- CSR build ----------------

__global__ void hist_k(const int* __restrict__ dst, int* __restrict__ deg) {
    int e = blockIdx.x * blockDim.x + threadIdx.x;
    if (e < N_EDGES) atomicAdd(&deg[dst[e]], 1);
}

__global__ __launch_bounds__(SCAN_BLK) void scan1_k(const int* __restrict__ deg,
                                                    int* __restrict__ blocksum) {
    __shared__ int wsum[SCAN_BLK / 64];
    int t = threadIdx.x;
    int i = blockIdx.x * SCAN_BLK + t;
    int v = (i < N_NODES) ? deg[i] : 0;
    #pragma unroll
    for (int s = 32; s > 0; s >>= 1) v += __shfl_down(v, s);
    if ((t & 63) == 0) wsum[t >> 6] = v;
    __syncthreads();
    if (t < SCAN_BLK / 64) {
        int x = wsum[t];
        #pragma unroll
        for (int s = SCAN_BLK / 128; s > 0; s >>= 1) x += __shfl_down(x, s);
        if (t == 0) blocksum[blockIdx.x] = x;
    }
}

// block-local exclusive scan + serial base over 40 blocksums
__global__ __launch_bounds__(SCAN_BLK) void scan3_k(const int* __restrict__ deg,
                                                    const int* __restrict__ blocksum,
                                                    int* __restrict__ offsets,
                                                    int* __restrict__ cursor) {
    __shared__ int sm[SCAN_BLK];
    __shared__ int base_s;
    int t = threadIdx.x;
    int i = blockIdx.x * SCAN_BLK + t;
    if (t == 0) {
        int b = 0;
        for (int j = 0; j < (int)blockIdx.x; j++) b += blocksum[j];
        base_s = b;
        if (blockIdx.x == N_SCAN_BLKS - 1)
            offsets[N_NODES] = b + blocksum[blockIdx.x];
    }
    int v = (i < N_NODES) ? deg[i] : 0;
    sm[t] = v;
    __syncthreads();
    for (int s = 1; s < SCAN_BLK; s <<= 1) {
        int u = (t >= s) ? sm[t - s] : 0;
        __syncthreads();
        sm[t] += u;
        __syncthreads();
    }
    if (i < N_NODES) {
        int excl = base_s + sm[t] - v;
        offsets[i] = excl;
        cursor[i] = excl;
    }
}

__global__ void place_k(const int* __restrict__ src, const int* __restrict__ dst,
                        int* __restrict__ cursor, int* __restrict__ src_sorted) {
    int e = blockIdx.x * blockDim.x + threadIdx.x;
    if (e < N_EDGES) {
        int p = atomicAdd(&cursor[dst[e]], 1);
        src_sorted[p] = src[e];
    }
}

// ---------------- x -> fp16 conversion ----------------

__global__ void xh_k(const float* __restrict__ x, _Float16* __restrict__ xh) {
    int i = blockIdx.x * blockDim.x + threadIdx.x;   // one per 8 elems
    if (i >= N_NODES * D_IN / 8) return;
    float4 a = ((const float4*)x)[i * 2];
    float4 b = ((const float4*)x)[i * 2 + 1];
    half8v h;
    h[0] = (_Float16)a.x; h[1] = (_Float16)a.y; h[2] = (_Float16)a.z; h[3] = (_Float16)a.w;
    h[4] = (_Float16)b.x; h[5] = (_Float16)b.y; h[6] = (_Float16)b.z; h[7] = (_Float16)b.w;
    ((half8v*)xh)[i] = h;
}

// ---------------- mean aggregation over fp16 rows (gather, 16B/lane, unroll-8) --------
// D fp16 per row; each lane owns 8 dims; 256/(D/8) nodes per block; fp32 accum.

template <int D>
__global__ __launch_bounds__(256) void aggh_k(const _Float16* __restrict__ feat,
                                              const int* __restrict__ offsets,
                                              const int* __restrict__ srcs,
                                              float* __restrict__ mean_out) {
    constexpr int LPN = D / 8;          // lanes per node (16 for D=128)
    constexpr int NPB = 256 / LPN;      // nodes per block (16)
    int t = threadIdx.x;
    int g = t / LPN;
    int q = t % LPN;
    int node = blockIdx.x * NPB + g;
    int beg = offsets[node];
    int end = offsets[node + 1];
    float acc[8] = {0.f, 0.f, 0.f, 0.f, 0.f, 0.f, 0.f, 0.f};
    int i = beg;
    for (; i + 8 <= end; i += 8) {
        half8v v[8];
        #pragma unroll
        for (int j = 0; j < 8; j++)
            v[j] = *(const half8v*)(feat + (size_t)srcs[i + j] * D + q * 8);
        #pragma unroll
        for (int j = 0; j < 8; j++) {
            #pragma unroll
            for (int k = 0; k < 8; k++) acc[k] += (float)v[j][k];
        }
    }
    for (; i < end; ++i) {
        half8v v = *(const half8v*)(feat + (size_t)srcs[i] * D + q * 8);
        #pragma unroll
        for (int k = 0; k < 8; k++) acc[k] += (float)v[k];
    }
    int cnt = end - beg;
    float inv = 1.0f / (float)(cnt > 1 ? cnt : 1);
    float4 r0, r1;
    r0.x = acc[0] * inv; r0.y = acc[1] * inv; r0.z = acc[2] * inv; r0.w = acc[3] * inv;
    r1.x = acc[4] * inv; r1.y = acc[5] * inv; r1.z = acc[6] * inv; r1.w = acc[7] * inv;
    *(float4*)(mean_out + (size_t)node * D + q * 8) = r0;
    *(float4*)(mean_out + (size_t)node * D + q * 8 + 4) = r1;
}

// ---------------- W split+transpose (all four weights, one launch) ----------------

__device__ __forceinline__ void wsplit_one(const float* W, int K, int N, int tid,
                                           short* Wt_hi, short* Wt_lo) {
    int k = tid / N, n = tid - k * N;
    float w = W[tid];
    unsigned short h = f2bf(w);
    unsigned short lo = f2bf(w - bf2f(h));
    Wt_hi[n * K + k] = (short)h;
    Wt_lo[n * K + k] = (short)lo;
}

__global__ void wsplit_all_k(const float* __restrict__ W1nb, const float* __restrict__ W1sf,
                             const float* __restrict__ W2nb, const float* __restrict__ W2sf,
                             short* __restrict__ o1nbh, short* __restrict__ o1nbl,
                             short* __restrict__ o1sfh, short* __restrict__ o1sfl,
                             short* __restrict__ o2nbh, short* __restrict__ o2nbl,
                             short* __restrict__ o2sfh, short* __restrict__ o2sfl) {
    int tid = blockIdx.x * blockDim.x + threadIdx.x;
    if (tid < 16384)      wsplit_one(W1nb, 128, 128, tid,          o1nbh, o1nbl);
    else if (tid < 32768) wsplit_one(W1sf, 128, 128, tid - 16384,  o1sfh, o1sfl);
    else if (tid < 40960) wsplit_one(W2nb, 128, 64,  tid - 32768,  o2nbh, o2nbl);
    else if (tid < 49152) wsplit_one(W2sf, 128, 64,  tid - 40960,  o2sfh, o2sfl);
}

// ---------------- layer-1 fused dual GEMM (unchanged structure) ----------------
// h1[32x64 tile] = relu(mean1@W1nb + x@W1self + b1); grid (1250, 2).

template <int NOUT>
__global__ __launch_bounds__(256) void sage_mfma_k(
    const float* __restrict__ A1, const float* __restrict__ A2,
    const short* __restrict__ W1h, const short* __restrict__ W1l,
    const short* __restrict__ W2h, const short* __restrict__ W2l,
    const float* __restrict__ bias, float* __restrict__ out) {
    __shared__ short wh_s[64 * 128];
    __shared__ short wl_s[64 * 128];

    const int t = threadIdx.x;
    const int w = t >> 6;
    const int l = t & 63;
    const int ln16 = l & 15;
    const int kgrp = l >> 4;
    const int arow = blockIdx.x * 32 + (w & 1) * 16 + ln16;
    const int colbase = blockIdx.y * 64;
    const int cw = (w >> 1) * 32;

    float4v acc[2];
    #pragma unroll
    for (int ct = 0; ct < 2; ct++) {
        float bv = bias[colbase + cw + ct * 16 + ln16];
        acc[ct] = (float4v){bv, bv, bv, bv};
    }

    for (int phase = 0; phase < 2; ++phase) {
        const float* __restrict__ A  = phase ? A2 : A1;
        const short* __restrict__ Wh = phase ? W2h : W1h;
        const short* __restrict__ Wl = phase ? W2l : W1l;

        __syncthreads();

        float4 a0[4], a1[4];
        const float* ap = A + (size_t)arow * 128 + kgrp * 8;
        #pragma unroll
        for (int kc = 0; kc < 4; kc++) {
            a0[kc] = *(const float4*)(ap + kc * 32);
            a1[kc] = *(const float4*)(ap + kc * 32 + 4);
        }

        #pragma unroll
        for (int it = 0; it < 4; it++) {
            int fid = t + it * 256;
            int r = fid >> 4, c = fid & 15;
            int gofs = (colbase + r) * 128 + c * 8;
            int byte = (r * 256 + c * 16) ^ ((r & 7) << 4);
            *(int4*)((char*)wh_s + byte) = *(const int4*)(Wh + gofs);
            *(int4*)((char*)wl_s + byte) = *(const int4*)(Wl + gofs);
        }

        short8v ah[4], al[4];
        #pragma unroll
        for (int kc = 0; kc < 4; kc++) {
            #pragma unroll
            for (int j = 0; j < 4; j++) {
                float f0 = (&a0[kc].x)[j];
                float f1 = (&a1[kc].x)[j];
                unsigned short h0 = f2bf(f0), h1 = f2bf(f1);
                ah[kc][j]     = (short)h0;
                ah[kc][j + 4] = (short)h1;
                al[kc][j]     = (short)f2bf(f0 - bf2f(h0));
                al[kc][j + 4] = (short)f2bf(f1 - bf2f(h1));
            }
        }

        __syncthreads();

        #pragma unroll
        for (int kc = 0; kc < 4; kc++) {
            #pragma unroll
            for (int ct = 0; ct < 2; ct++) {
                int col = cw + ct * 16 + ln16;
                int byte = (col * 256 + kc * 64 + kgrp * 16) ^ ((col & 7) << 4);
                short8v bh = *(const short8v*)((const char*)wh_s + byte);
                short8v bl = *(const short8v*)((const char*)wl_s + byte);
                acc[ct] = __builtin_amdgcn_mfma_f32_16x16x32_bf16(ah[kc], bh, acc[ct], 0, 0, 0);
                acc[ct] = __builtin_amdgcn_mfma_f32_16x16x32_bf16(ah[kc], bl, acc[ct], 0, 0, 0);
                acc[ct] = __builtin_amdgcn_mfma_f32_16x16x32_bf16(al[kc], bh, acc[ct], 0, 0, 0);
            }
        }
    }

    #pragma unroll
    for (int ct = 0; ct < 2; ct++) {
        #pragma unroll
        for (int r = 0; r < 4; r++) {
            int row = blockIdx.x * 32 + (w & 1) * 16 + kgrp * 4 + r;
            int col = colbase + cw + ct * 16 + ln16;
            out[(size_t)row * NOUT + col] = fmaxf(acc[ct][r], 0.f);
        }
    }
}

// ---------------- layer-2 pre-transform GEMM ----------------
// nb-part (h1@W2nb) written as fp16 to z2nb[N,64] (gather payload);
// self-part (h1@W2self + b2) written fp32 to zself[N,64].

__global__ __launch_bounds__(256) void gemm2_k(
    const float* __restrict__ A,
    const short* __restrict__ Wnbh, const short* __restrict__ Wnbl,
    const short* __restrict__ Wsfh, const short* __restrict__ Wsfl,
    const float* __restrict__ b2,
    _Float16* __restrict__ z2nb, float* __restrict__ zself) {
    __shared__ short wh_s[64 * 128];
    __shared__ short wl_s[64 * 128];

    const int t = threadIdx.x;
    const int w = t >> 6;
    const int l = t & 63;
    const int ln16 = l & 15;
    const int kgrp = l >> 4;
    const int arow = blockIdx.x * 32 + (w & 1) * 16 + ln16;
    const int ysel = blockIdx.y;          // 0: nb(fp16), 1: self(+b2, fp32)
    const int cw = (w >> 1) * 32;

    const short* __restrict__ Wh = ysel ? Wsfh : Wnbh;
    const short* __restrict__ Wl = ysel ? Wsfl : Wnbl;

    float4v acc[2];
    #pragma unroll
    for (int ct = 0; ct < 2; ct++) {
        float bv = ysel ? b2[cw + ct * 16 + ln16] : 0.f;
        acc[ct] = (float4v){bv, bv, bv, bv};
    }

    float4 a0[4], a1[4];
    const float* ap = A + (size_t)arow * 128 + kgrp * 8;
    #pragma unroll
    for (int kc = 0; kc < 4; kc++) {
        a0[kc] = *(const float4*)(ap + kc * 32);
        a1[kc] = *(const float4*)(ap + kc * 32 + 4);
    }

    #pragma unroll
    for (int it = 0; it < 4; it++) {
        int fid = t + it * 256;
        int r = fid >> 4, c = fid & 15;
        int gofs = r * 128 + c * 8;
        int byte = (r * 256 + c * 16) ^ ((r & 7) << 4);
        *(int4*)((char*)wh_s + byte) = *(const int4*)(Wh + gofs);
        *(int4*)((char*)wl_s + byte) = *(const int4*)(Wl + gofs);
    }

    short8v ah[4], al[4];
    #pragma unroll
    for (int kc = 0; kc < 4; kc++) {
        #pragma unroll
        for (int j = 0; j < 4; j++) {
            float f0 = (&a0[kc].x)[j];
            float f1 = (&a1[kc].x)[j];
            unsigned short h0 = f2bf(f0), h1 = f2bf(f1);
            ah[kc][j]     = (short)h0;
            ah[kc][j + 4] = (short)h1;
            al[kc][j]     = (short)f2bf(f0 - bf2f(h0));
            al[kc][j + 4] = (short)f2bf(f1 - bf2f(h1));
        }
    }

    __syncthreads();

    #pragma unroll
    for (int kc = 0; kc < 4; kc++) {
        #pragma unroll
        for (int ct = 0; ct < 2; ct++) {
            int col = cw + ct * 16 + ln16;
            int byte = (col * 256 + kc * 64 + kgrp * 16) ^ ((col & 7) << 4);
            short8v bh = *(const short8v*)((const char*)wh_s + byte);
            short8v bl = *(const short8v*)((const char*)wl_s + byte);
            acc[ct] = __builtin_amdgcn_mfma_f32_16x16x32_bf16(ah[kc], bh, acc[ct], 0, 0, 0);
            acc[ct] = __builtin_amdgcn_mfma_f32_16x16x32_bf16(ah[kc], bl, acc[ct], 0, 0, 0);
            acc[ct] = __builtin_amdgcn_mfma_f32_16x16x32_bf16(al[kc], bh, acc[ct], 0, 0, 0);
        }
    }

    #pragma unroll
    for (int ct = 0; ct < 2; ct++) {
        #pragma unroll
        for (int r = 0; r < 4; r++) {
            int row = blockIdx.x * 32 + (w & 1) * 16 + kgrp * 4 + r;
            int col = cw + ct * 16 + ln16;
            if (ysel == 0) z2nb[(size_t)row * 64 + col] = (_Float16)acc[ct][r];
            else           zself[(size_t)row * 64 + col] = acc[ct][r];
        }
    }
}

// ---------------- fused layer-2 agg + epilogue + FC ----------------
// Per node: mean over fp16 z2nb neighbor rows (64d), + fp32 self, relu -> emb;
// then logits = emb@Wfc + bfc. 32 nodes x 8 lanes per 256-thread block.

__global__ __launch_bounds__(256) void agg2final_k(const _Float16* __restrict__ z2nb,
                                                   const float* __restrict__ zself,
                                                   const int* __restrict__ offsets,
                                                   const int* __restrict__ srcs,
                                                   const float* __restrict__ Wfc,
                                                   const float* __restrict__ bfc,
                                                   float* __restrict__ emb,
                                                   float* __restrict__ logits) {
    __shared__ float es[32][68];
    int t = threadIdx.x;
    int g = t >> 3;          // node in block (0..31)
    int q = t & 7;           // lane: dims [q*8, q*8+8)
    int node = blockIdx.x * 32 + g;
    int beg = offsets[node];
    int end = offsets[node + 1];
    float acc[8] = {0.f, 0.f, 0.f, 0.f, 0.f, 0.f, 0.f, 0.f};
    int i = beg;
    for (; i + 8 <= end; i += 8) {
        half8v v[8];
        #pragma unroll
        for (int j = 0; j < 8; j++)
            v[j] = *(const half8v*)(z2nb + (size_t)srcs[i + j] * 64 + q * 8);
        #pragma unroll
        for (int j = 0; j < 8; j++) {
            #pragma unroll
            for (int k = 0; k < 8; k++) acc[k] += (float)v[j][k];
        }
    }
    for (; i < end; ++i) {
        half8v v = *(const half8v*)(z2nb + (size_t)srcs[i] * 64 + q * 8);
        #pragma unroll
        for (int k = 0; k < 8; k++) acc[k] += (float)v[k];
    }
    int cnt = end - beg;
    float inv = 1.0f / (float)(cnt > 1 ? cnt : 1);
    float4 s0 = *(const float4*)(zself + (size_t)node * 64 + q * 8);
    float4 s1 = *(const float4*)(zself + (size_t)node * 64 + q * 8 + 4);
    float e[8];
    e[0] = fmaxf(acc[0] * inv + s0.x, 0.f);
    e[1] = fmaxf(acc[1] * inv + s0.y, 0.f);
    e[2] = fmaxf(acc[2] * inv + s0.z, 0.f);
    e[3] = fmaxf(acc[3] * inv + s0.w, 0.f);
    e[4] = fmaxf(acc[4] * inv + s1.x, 0.f);
    e[5] = fmaxf(acc[5] * inv + s1.y, 0.f);
    e[6] = fmaxf(acc[6] * inv + s1.z, 0.f);
    e[7] = fmaxf(acc[7] * inv + s1.w, 0.f);
    float4 o0 = {e[0], e[1], e[2], e[3]};
    float4 o1 = {e[4], e[5], e[6], e[7]};
    *(float4*)(emb + (size_t)node * 64 + q * 8) = o0;
    *(float4*)(emb + (size_t)node * 64 + q * 8 + 4) = o1;
    #pragma unroll
    for (int k = 0; k < 8; k++) es[g][q * 8 + k] = e[k];
    __syncthreads();
    // 32 nodes x 40 cols = 1280 outputs; 5 per thread
    #pragma unroll
    for (int j = 0; j < 5; j++) {
        int o = t + 256 * j;
        int ng = o / D_OUT;
        int c = o - ng * D_OUT;
        int gnode = blockIdx.x * 32 + ng;
        float a = bfc[c];
        #pragma unroll
        for (int k = 0; k < 64; k++) a += es[ng][k] * Wfc[k * D_OUT + c];
        logits[(size_t)gnode * D_OUT + c] = a;
    }
}

// ---------------- launch ----------------

extern "C" void kernel_launch(void* const* d_in, const int* in_sizes, int n_in,
                              void* d_out, int out_size, void* d_ws, size_t ws_size,
                              hipStream_t stream) {
    const float* x       = (const float*)d_in[0];
    const int*   ei      = (const int*)d_in[1];
    const float* W1_nb   = (const float*)d_in[2];
    const float* b1      = (const float*)d_in[3];
    const float* W1_self = (const float*)d_in[4];
    const float* W2_nb   = (const float*)d_in[5];
    const float* b2      = (const float*)d_in[6];
    const float* W2_self = (const float*)d_in[7];
    const float* Wfc     = (const float*)d_in[8];
    const float* bfc     = (const float*)d_in[9];

    const int* src = ei;
    const int* dst = ei + N_EDGES;

    // workspace layout (44.2MB total — proven footprint from R6-R8):
    //   [ints 3.0MB][region1 20.5MB: mean1, later z2nb+zself]
    //   [region2 20.5MB: xh (first 10.2MB, dead after aggh) -> h1 (whole)]
    //   [weight splits 0.2MB]
    char* w = (char*)d_ws;
    int* deg        = (int*)w;                         // N
    int* offsets    = deg + N_NODES;                   // N+1
    int* cursor     = offsets + (N_NODES + 1);         // N
    int* blocksum   = cursor + N_NODES;                // 40
    int* src_sorted = blocksum + N_SCAN_BLKS;          // E
    size_t int_elems = (size_t)N_NODES * 3 + 1 + N_SCAN_BLKS + N_EDGES;
    size_t int_bytes = (int_elems * 4 + 15) & ~(size_t)15;
    float* mean1 = (float*)(w + int_bytes);            // N*128 fp32 (dead after gemm1)
    _Float16* z2nb = (_Float16*)mean1;                 // N*64 fp16 (overlays mean1)
    float* zself = (float*)((char*)mean1 + (size_t)N_NODES * 64 * sizeof(_Float16));
    float* h1    = mean1 + (size_t)N_NODES * 128;      // N*128 fp32 (region2)
    _Float16* xh = (_Float16*)h1;                      // N*128 fp16 — OVERLAYS h1:
                                                       // xh written step 0, read by aggh
                                                       // (step 2a); h1 first written by
                                                       // sage_mfma (step 2b, stream-ordered
                                                       // after aggh) -> no aliasing hazard.
    short* w1nb_h   = (short*)(h1 + (size_t)N_NODES * 128);
    short* w1nb_l   = w1nb_h + 128 * 128;
    short* w1self_h = w1nb_l + 128 * 128;
    short* w1self_l = w1self_h + 128 * 128;
    short* w2nb_h   = w1self_l + 128 * 128;
    short* w2nb_l   = w2nb_h + 128 * 64;
    short* w2self_h = w2nb_l + 128 * 64;
    short* w2self_l = w2self_h + 128 * 64;

    float* emb    = (float*)d_out;                     // [N, 64]
    float* logits = emb + (size_t)N_NODES * D_H2;      // [N, 40]

    // 0. weight split/transpose + x->fp16
    wsplit_all_k<<<(49152 + 255) / 256, 256, 0, stream>>>(
        W1_nb, W1_self, W2_nb, W2_self,
        w1nb_h, w1nb_l, w1self_h, w1self_l, w2nb_h, w2nb_l, w2self_h, w2self_l);
    xh_k<<<(N_NODES * D_IN / 8 + 255) / 256, 256, 0, stream>>>(x, xh);

    // 1. CSR build
    hipMemsetAsync(deg, 0, N_NODES * sizeof(int), stream);
    hist_k<<<(N_EDGES + 255) / 256, 256, 0, stream>>>(dst, deg);
    scan1_k<<<N_SCAN_BLKS, SCAN_BLK, 0, stream>>>(deg, blocksum);
    scan3_k<<<N_SCAN_BLKS, SCAN_BLK, 0, stream>>>(deg, blocksum, offsets, cursor);
    place_k<<<(N_EDGES + 255) / 256, 256, 0, stream>>>(src, dst, cursor, src_sorted);

    // 2. layer 1: mean1 = agg(xh); h1 = relu(mean1@W1nb + x@W1self + b1)
    //    (sage_mfma's h1 writes overwrite xh — xh is dead after aggh)
    aggh_k<128><<<N_NODES / 16, 256, 0, stream>>>(xh, offsets, src_sorted, mean1);
    sage_mfma_k<128><<<dim3(N_NODES / 32, 2), 256, 0, stream>>>(
        mean1, x, w1nb_h, w1nb_l, w1self_h, w1self_l, b1, h1);

    // 3. layer 2 pre-transform: z2nb(fp16) = h1@W2nb ; zself = h1@W2self + b2
    //    (writes overlay mean1's region — mean1 is dead after gemm1)
    gemm2_k<<<dim3(N_NODES / 32, 2), 256, 0, stream>>>(
        h1, w2nb_h, w2nb_l, w2self_h, w2self_l, b2, z2nb, zself);

    // 4. fused layer-2 agg + relu epilogue + FC head
    agg2final_k<<<N_NODES / 32, 256, 0, stream>>>(
        z2nb, zself, offsets, src_sorted, Wfc, bfc, emb, logits);
}